// Round 7
// baseline (209.029 us; speedup 1.0000x reference)
//
#include <hip/hip_runtime.h>

// CombinedLoss: chamfer(pred,gt) + 0.1*repulsion(pred,k=4) + 0.01*(1 - mean(n_pred . n_gt))
// B=8, N=2048, fp32 in, fp32 scalar out.
// Normals match np.linalg.eigh (LAPACK ssyevd) signs point-by-point via faithful
// fp32 ssytd2+ssteqr+sormtr emulation (R3-R7: absmax 0.0).
// R8: branchless sorted-chain top-10 per wave-slice, exact top-16 via 8x10 pool
// merge + violation-detect + rare rescan fallback.
// R9: eigensolver state in named registers (cndmask dynamic indexing).
// R13: 8-way masked tail REGRESSED (exec-masked lanes still consume issue slots).
// R14: full-pack wave-0 tail + fused fin. 162.3us. Occupancy decomposition:
// scan phase ~41us, wave-0 tail ~71us at 0.5 waves/SIMD (latency-exposed; 7/8
// waves retired). Launch overhead measured ~1-2us/launch (R10's ~10us theory wrong).
// R15: TAIL AMPUTATED from scan kernel. Kernel A = scan only; waves store their
// sorted top-10 + chamfer min straight from registers to global (coalesced,
// ~11.5MB) and exit together -> wall ~= scan phase. Kernel B = tail at FULL
// packing and 8 waves/CU (64 blocks x 512): lane = query; merge from global
// keys with bit-exact early-exit (chain16 is a no-op when kk >= k16[15], so
// __any-guarded skip preserves results exactly); violation fallback + cov
// gather recompute from global with identical fp32 ops; eigensolver unchanged.
// fin unchanged (exact per-thread fp32 dot order). 3 launches.

#define NB 8
#define NP 2048
#define KW 10     // per-slice kept keys
#define KN 16
#define NQ (2 * NB * NP)   // 32768 queries (both clouds)

// ---------------- LAPACK helpers (fp32, faithful — DO NOT TOUCH) ----------------

__device__ __forceinline__ float f_slapy2(float x, float y) {
    float xa = fabsf(x), ya = fabsf(y);
    float w = fmaxf(xa, ya), zm = fminf(xa, ya);
    if (zm == 0.f) return w;
    float q = zm / w;
    return w * sqrtf(1.f + q * q);
}

// LAPACK >=3.10 slartg convention: c >= 0 always.
__device__ __forceinline__ void f_slartg(float f, float g, float* cs, float* sn, float* r) {
    if (g == 0.f) { *cs = 1.f; *sn = 0.f; *r = f; }
    else if (f == 0.f) { *cs = 0.f; *sn = copysignf(1.f, g); *r = fabsf(g); }
    else {
        float d = sqrtf(__fadd_rn(__fmul_rn(f, f), __fmul_rn(g, g)));
        *cs = fabsf(f) / d;
        *r  = copysignf(d, f);
        *sn = g / *r;
    }
}

__device__ void f_slaev2(float a, float b, float c,
                         float* rt1, float* rt2, float* cs1, float* sn1) {
    float sm = a + c;
    float df = a - c;
    float adf = fabsf(df);
    float tb = b + b;
    float ab = fabsf(tb);
    float acmx, acmn;
    if (fabsf(a) > fabsf(c)) { acmx = a; acmn = c; } else { acmx = c; acmn = a; }
    float rt;
    if (adf > ab)      { float q = ab / adf; rt = adf * sqrtf(1.f + q * q); }
    else if (adf < ab) { float q = adf / ab; rt = ab * sqrtf(1.f + q * q); }
    else               rt = ab * sqrtf(2.f);
    int sgn1;
    if (sm < 0.f) {
        *rt1 = 0.5f * (sm - rt); sgn1 = -1;
        *rt2 = (acmx / *rt1) * acmn - (b / *rt1) * b;
    } else if (sm > 0.f) {
        *rt1 = 0.5f * (sm + rt); sgn1 = 1;
        *rt2 = (acmx / *rt1) * acmn - (b / *rt1) * b;
    } else {
        *rt1 = 0.5f * rt; *rt2 = -0.5f * rt; sgn1 = 1;
    }
    float cs; int sgn2;
    if (df >= 0.f) { cs = df + rt; sgn2 = 1; }
    else           { cs = df - rt; sgn2 = -1; }
    float acs = fabsf(cs);
    if (acs > ab) {
        float ct = -tb / cs;
        *sn1 = 1.f / sqrtf(1.f + ct * ct);
        *cs1 = ct * *sn1;
    } else {
        if (ab == 0.f) { *cs1 = 1.f; *sn1 = 0.f; }
        else {
            float tn = -cs / tb;
            *cs1 = 1.f / sqrtf(1.f + tn * tn);
            *sn1 = tn * *cs1;
        }
    }
    if (sgn1 == sgn2) { float tn = *cs1; *cs1 = -*sn1; *sn1 = tn; }
}

// --------- register-resident dynamic indexing (R9: replaces scratch arrays) ---------
// Selection only — bit-exact with array loads/stores; compiles to v_cndmask, no memory.

__device__ __forceinline__ float get3(float a, float b, float c, int i) {
    return i == 0 ? a : (i == 1 ? b : c);
}
__device__ __forceinline__ void set3(float& a, float& b, float& c, int i, float v) {
    a = (i == 0) ? v : a;
    b = (i == 1) ? v : b;
    c = (i == 2) ? v : c;
}
__device__ __forceinline__ float get2(float a, float b, int i) { return i == 0 ? a : b; }
__device__ __forceinline__ void set2(float& a, float& b, int i, float v) {
    a = (i == 0) ? v : a;
    b = (i == 1) ? v : b;
}

#define DGET(i)    get3(dd0, dd1, dd2, (i))
#define DSET(i, v) set3(dd0, dd1, dd2, (i), (v))
#define EGET(i)    get2(ee0, ee1, (i))
#define ESET(i, v) set2(ee0, ee1, (i), (v))
#define ZGET(r, c)    get3(z##r##0, z##r##1, z##r##2, (c))
#define ZSET(r, c, v) set3(z##r##0, z##r##1, z##r##2, (c), (v))
// Two-column Givens update: cols (ca,cb) <- (cc*ca - ss*cb, ss*ca + cc*cb), all 3 rows.
#define ZROT(r, ca, cb, cc, ss) { float zt_ = ZGET(r, (ca)); float zb_ = ZGET(r, (cb)); \
    ZSET(r, (ca), (cc) * zt_ - (ss) * zb_); ZSET(r, (cb), (ss) * zt_ + (cc) * zb_); }
#define ZROT3(ca, cb, cc, ss) { ZROT(0, (ca), (cb), (cc), (ss)) ZROT(1, (ca), (cb), (cc), (ss)) ZROT(2, (ca), (cb), (cc), (ss)) }

// fp32 ssyevd for a 3x3 symmetric matrix (lower triangle given), returns
// eigenvector of the SMALLEST eigenvalue, with LAPACK's sign convention.
__device__ void ssyevd3_evec0(float a00, float a10, float a20,
                              float a11, float a21, float a22,
                              float* ox, float* oy, float* oz) {
    // ---- ssytd2('L') ----
    float dd0, dd1, dd2, ee0, ee1;
    float tau = 0.f, v2 = 0.f;
    float xnorm = fabsf(a20);
    if (xnorm == 0.f) {
        tau = 0.f;
        dd0 = a00; dd1 = a11; dd2 = a22; ee0 = a10; ee1 = a21;
    } else {
        float beta = -copysignf(f_slapy2(a10, xnorm), a10);
        tau = (beta - a10) / beta;
        float inv = 1.f / (a10 - beta);
        v2 = a20 * inv;
        float x1 = tau * (a11 + a21 * v2);
        float x2 = tau * (a21 + a22 * v2);
        float alpha = -0.5f * tau * (x1 + x2 * v2);
        float w1 = x1 + alpha;
        float w2 = x2 + alpha * v2;
        float b11 = a11 - 2.f * w1;
        float b21 = a21 - v2 * w1 - w2;
        float b22 = a22 - 2.f * (v2 * w2);
        dd0 = a00; dd1 = b11; dd2 = b22; ee0 = beta; ee1 = b21;
    }
    // ---- ssteqr('I', n=3) ----
    const float eps    = 5.9604645e-08f;
    const float eps2   = eps * eps;
    const float safmin = 1.1754944e-38f;
    const float ssfmax = sqrtf(1.f / safmin) / 3.f;
    const float ssfmin = sqrtf(safmin) / eps2;
    const int n = 3, nmaxit = 90;
    float z00 = 1.f, z01 = 0.f, z02 = 0.f;
    float z10 = 0.f, z11 = 1.f, z12 = 0.f;
    float z20 = 0.f, z21 = 0.f, z22 = 1.f;
    int jtot = 0;
    int l1 = 1;

    while (true) {
        if (l1 > n) break;
        if (l1 > 1) ESET(l1 - 2, 0.f);
        int m = n;
        {   // for (mi = l1; mi <= n-1; ++mi) with first-hit break
            bool found = false;
            #pragma unroll
            for (int mi = 1; mi <= 2; ++mi) {
                if (!found && mi >= l1) {
                    float tst = fabsf(EGET(mi - 1));
                    if (tst == 0.f) { m = mi; found = true; }
                    else if (tst <= (sqrtf(fabsf(DGET(mi - 1))) * sqrtf(fabsf(DGET(mi)))) * eps) {
                        ESET(mi - 1, 0.f); m = mi; found = true;
                    }
                }
            }
        }
        int l = l1, lsv = l, lend = m, lendsv = lend;
        l1 = m + 1;
        if (lend == l) continue;

        float anorm = 0.f;
        #pragma unroll
        for (int i = 1; i <= 3; ++i)
            if (i >= l && i <= lend) anorm = fmaxf(anorm, fabsf(DGET(i - 1)));
        #pragma unroll
        for (int i = 1; i <= 2; ++i)
            if (i >= l && i <= lend - 1) anorm = fmaxf(anorm, fabsf(EGET(i - 1)));
        int iscale = 0; float sclto = 1.f;
        if (anorm == 0.f) continue;
        if (anorm > ssfmax) { iscale = 1; sclto = ssfmax; }
        else if (anorm < ssfmin) { iscale = 2; sclto = ssfmin; }
        if (iscale) {
            float mul = sclto / anorm;
            #pragma unroll
            for (int i = 1; i <= 3; ++i)
                if (i >= l && i <= lend) DSET(i - 1, DGET(i - 1) * mul);
            #pragma unroll
            for (int i = 1; i <= 2; ++i)
                if (i >= l && i <= lend - 1) ESET(i - 1, EGET(i - 1) * mul);
        }
        if (fabsf(DGET(lend - 1)) < fabsf(DGET(l - 1))) { lend = lsv; l = lendsv; }

        if (lend > l) {
            // QL
            while (true) {
                int mq = lend;
                if (l != lend) {
                    bool found = false;
                    #pragma unroll
                    for (int i = 1; i <= 2; ++i) {
                        if (!found && i >= l && i <= lend - 1) {
                            float ei = EGET(i - 1);
                            float tst = ei * ei;
                            if (tst <= (eps2 * fabsf(DGET(i - 1))) * fabsf(DGET(i)) + safmin) { mq = i; found = true; }
                        }
                    }
                }
                if (mq < lend) ESET(mq - 1, 0.f);
                float p = DGET(l - 1);
                if (mq == l) { DSET(l - 1, p); l = l + 1; if (l <= lend) continue; break; }
                if (mq == l + 1) {
                    float rt1, rt2, c, s;
                    f_slaev2(DGET(l - 1), EGET(l - 1), DGET(l), &rt1, &rt2, &c, &s);
                    ZROT3(l, l - 1, c, s);
                    DSET(l - 1, rt1); DSET(l, rt2); ESET(l - 1, 0.f);
                    l += 2; if (l <= lend) continue; break;
                }
                if (jtot == nmaxit) break;
                jtot++;
                float g = (DGET(l) - p) / (2.f * EGET(l - 1));
                float r = f_slapy2(g, 1.f);
                g = DGET(mq - 1) - p + EGET(l - 1) / (g + copysignf(r, g));
                float s = 1.f, c = 1.f; p = 0.f;
                float cw0 = 0.f, cw1 = 0.f, sw0 = 0.f, sw1 = 0.f;
                // for (i = mq-1; i >= l; --i)
                #pragma unroll
                for (int i = 2; i >= 1; --i) {
                    if (i <= mq - 1 && i >= l) {
                        float f = s * EGET(i - 1);
                        float b = c * EGET(i - 1);
                        f_slartg(g, f, &c, &s, &r);
                        if (i != mq - 1) ESET(i, r);
                        g = DGET(i) - p;
                        r = (DGET(i - 1) - g) * s + 2.f * c * b;
                        p = s * r;
                        DSET(i, g + p);
                        g = c * r - b;
                        set2(cw0, cw1, i - l, c);
                        set2(sw0, sw1, i - l, -s);
                    }
                }
                // for (j = mq-l; j >= 1; --j)
                #pragma unroll
                for (int j = 2; j >= 1; --j) {
                    if (j <= mq - l) {
                        float cj = get2(cw0, cw1, j - 1), sj = get2(sw0, sw1, j - 1);
                        int c0 = l - 1 + (j - 1);
                        ZROT3(c0 + 1, c0, cj, sj);
                    }
                }
                DSET(l - 1, DGET(l - 1) - p);
                ESET(l - 1, g);
            }
        } else {
            // QR
            while (true) {
                int mq = lend;
                if (l != lend) {
                    bool found = false;
                    // for (i = l; i >= lend+1; --i)
                    #pragma unroll
                    for (int i = 3; i >= 2; --i) {
                        if (!found && i <= l && i >= lend + 1) {
                            float ei = EGET(i - 2);
                            float tst = ei * ei;
                            if (tst <= (eps2 * fabsf(DGET(i - 1))) * fabsf(DGET(i - 2)) + safmin) { mq = i; found = true; }
                        }
                    }
                }
                if (mq > lend) ESET(mq - 2, 0.f);
                float p = DGET(l - 1);
                if (mq == l) { DSET(l - 1, p); l = l - 1; if (l >= lend) continue; break; }
                if (mq == l - 1) {
                    float rt1, rt2, c, s;
                    f_slaev2(DGET(l - 2), EGET(l - 2), DGET(l - 1), &rt1, &rt2, &c, &s);
                    ZROT3(l - 1, l - 2, c, s);
                    DSET(l - 2, rt1); DSET(l - 1, rt2); ESET(l - 2, 0.f);
                    l -= 2; if (l >= lend) continue; break;
                }
                if (jtot == nmaxit) break;
                jtot++;
                float g = (DGET(l - 2) - p) / (2.f * EGET(l - 2));
                float r = f_slapy2(g, 1.f);
                g = DGET(mq - 1) - p + EGET(l - 2) / (g + copysignf(r, g));
                float s = 1.f, c = 1.f; p = 0.f;
                float cw0 = 0.f, cw1 = 0.f, sw0 = 0.f, sw1 = 0.f;
                // for (i = mq; i <= l-1; ++i)
                #pragma unroll
                for (int i = 1; i <= 2; ++i) {
                    if (i >= mq && i <= l - 1) {
                        float f = s * EGET(i - 1);
                        float b = c * EGET(i - 1);
                        f_slartg(g, f, &c, &s, &r);
                        if (i != mq) ESET(i - 2, r);
                        g = DGET(i - 1) - p;
                        r = (DGET(i) - g) * s + 2.f * c * b;
                        p = s * r;
                        DSET(i - 1, g + p);
                        g = c * r - b;
                        set2(cw0, cw1, i - mq, c);
                        set2(sw0, sw1, i - mq, s);
                    }
                }
                // for (j = 1; j <= l-mq; ++j)
                #pragma unroll
                for (int j = 1; j <= 2; ++j) {
                    if (j <= l - mq) {
                        float cj = get2(cw0, cw1, j - 1), sj = get2(sw0, sw1, j - 1);
                        int c0 = mq - 1 + (j - 1);
                        ZROT3(c0 + 1, c0, cj, sj);
                    }
                }
                DSET(l - 1, DGET(l - 1) - p);
                ESET(l - 2, g);
            }
        }
        if (iscale) {
            float mul = anorm / sclto;
            #pragma unroll
            for (int i = 1; i <= 3; ++i)
                if (i >= lsv && i <= lendsv) DSET(i - 1, DGET(i - 1) * mul);
            #pragma unroll
            for (int i = 1; i <= 2; ++i)
                if (i >= lsv && i <= lendsv - 1) ESET(i - 1, EGET(i - 1) * mul);
        }
        if (jtot >= nmaxit) break;
    }

    // sort ascending (column swaps — no sign change)
    #pragma unroll
    for (int ii = 2; ii <= 3; ++ii) {
        int i = ii - 1, k = i;
        float p = DGET(i - 1);
        #pragma unroll
        for (int j = ii; j <= 3; ++j)
            if (DGET(j - 1) < p) { k = j; p = DGET(j - 1); }
        if (k != i) {
            DSET(k - 1, DGET(i - 1)); DSET(i - 1, p);
            { float t0 = ZGET(0, i - 1); ZSET(0, i - 1, ZGET(0, k - 1)); ZSET(0, k - 1, t0); }
            { float t1 = ZGET(1, i - 1); ZSET(1, i - 1, ZGET(1, k - 1)); ZSET(1, k - 1, t1); }
            { float t2 = ZGET(2, i - 1); ZSET(2, i - 1, ZGET(2, k - 1)); ZSET(2, k - 1, t2); }
        }
    }
    // sormtr('L','L','N')
    float r0 = z00, r1 = z10, r2 = z20;
    if (tau != 0.f) {
        float sum = r1 + v2 * r2;
        r1 -= tau * sum;
        r2 -= tau * (v2 * sum);
    }
    *ox = r0; *oy = r1; *oz = r2;
}

// ---------------- common ----------------

__device__ __forceinline__ float dot_rn(float ax, float ay, float az,
                                        float bx, float by, float bz) {
    return __fadd_rn(__fadd_rn(__fmul_rn(ax, bx), __fmul_rn(ay, by)), __fmul_rn(az, bz));
}

// Branchless sorted-chain inserts: keys ascending; drops the largest.
__device__ __forceinline__ void chain10(unsigned k[KW], unsigned x) {
    unsigned t = x;
    #pragma unroll
    for (int s = 0; s < KW; ++s) {
        unsigned lo = k[s] < t ? k[s] : t;
        unsigned hi = k[s] < t ? t : k[s];
        k[s] = lo; t = hi;
    }
}
__device__ __forceinline__ void chain16(unsigned k[KN], unsigned x) {
    unsigned t = x;
    #pragma unroll
    for (int s = 0; s < KN; ++s) {
        unsigned lo = k[s] < t ? k[s] : t;
        unsigned hi = k[s] < t ? t : k[s];
        k[s] = lo; t = hi;
    }
}

// ---------------- Kernel A: scan only ----------------
// 512 blocks x 512 threads (8 waves), 2 blocks/CU (64KB LDS). Wave w scans
// interleaved slice j=8t+w keeping branchless sorted top-10 per lane-query +
// chamfer partial min, then stores keys+min straight to global (coalesced per
// (s,wave): 64 consecutive u32) and exits. No tail, no second barrier.
__global__ __launch_bounds__(512, 4) void scan_kernel(
    const float* __restrict__ pred, const float* __restrict__ gt,
    unsigned* __restrict__ kbuf_g, float* __restrict__ mbuf_g)
{
    __shared__ float4 sHome[NP];            // (x,y,z,|p|^2)  32 KB
    __shared__ float4 sOther[NP];           // (x,y,z,0)      32 KB

    int bi = blockIdx.x;
    bool predHome = bi < NB * 32;
    int lb = predHome ? bi : bi - NB * 32;
    int b = lb >> 5;
    int tile = lb & 31;
    int tid  = threadIdx.x;
    int wave = tid >> 6;
    int lane = tid & 63;

    const float* home  = (predHome ? pred : gt) + (size_t)b * NP * 3;
    const float* other = (predHome ? gt : pred) + (size_t)b * NP * 3;

    for (int t = tid; t < NP; t += 512) {
        float hx = home[3 * t], hy = home[3 * t + 1], hz = home[3 * t + 2];
        sHome[t] = make_float4(hx, hy, hz, dot_rn(hx, hy, hz, hx, hy, hz));
        float ox = other[3 * t], oy = other[3 * t + 1], oz = other[3 * t + 2];
        sOther[t] = make_float4(ox, oy, oz, 0.f);
    }
    __syncthreads();

    int im = tile * 64 + lane;              // original index of this lane's query
    float4 qv = sHome[im];
    float qx = qv.x, qy = qv.y, qz = qv.z, qq = qv.w;

    unsigned keys[KW];
    #pragma unroll
    for (int s = 0; s < KW; ++s) keys[s] = 0x7F800000u | (unsigned)s;  // sorted inf seeds

    float minv = 1e30f;

    for (int t = 0; t < NP / 8; ++t) {
        int jj = (t << 3) | wave;
        float4 h = sHome[jj];                                  // broadcast b128
        float dotj = dot_rn(qx, qy, qz, h.x, h.y, h.z);
        float d2 = __fsub_rn(__fadd_rn(qq, h.w), __fmul_rn(2.f, dotj));
        chain10(keys, (__float_as_uint(d2) & 0xFFFFF800u) | (unsigned)jj);
        float4 o = sOther[jj];                                 // broadcast b128
        float ex = qx - o.x, ey = qy - o.y, ez = qz - o.z;
        minv = fminf(minv, fmaf(ex, ex, fmaf(ey, ey, ez * ez)));
    }

    // store sorted top-10 + chamfer min straight to global (coalesced per (s,wave))
    size_t gq = (size_t)(predHome ? 0 : NB * NP) + (size_t)b * NP + im;
    #pragma unroll
    for (int s = 0; s < KW; ++s)
        kbuf_g[(size_t)(s * 8 + wave) * NQ + gq] = keys[s];
    mbuf_g[(size_t)wave * NQ + gq] = minv;
}

// ---------------- Kernel B: packed tail ----------------
// 64 blocks x 512 threads = 512 fully-packed waves (8 waves/CU = 2/SIMD).
// Lane = query gq: merge 8x10 global keys -> exact top-16 (chain16 insert with
// provably-no-op skip when kk >= k16[15]), violation-detect + rare rescan from
// global points (bit-identical fp32: dot_rn recompute), repulsion, covariance
// gather from global (values identical to kernel A's staging), in-register
// ssyevd, normal store, per-block cd/rep partial.
__global__ __launch_bounds__(512) void tail_kernel(
    const float* __restrict__ pred, const float* __restrict__ gt,
    const unsigned* __restrict__ kbuf_g, const float* __restrict__ mbuf_g,
    float* __restrict__ normals, double* __restrict__ cdpart)
{
    __shared__ double wsum[8];
    int tid = threadIdx.x;
    int wave = tid >> 6, lane = tid & 63;
    size_t gq = (size_t)blockIdx.x * 512 + tid;

    bool predHome = gq < (size_t)(NB * NP);
    int gi = predHome ? (int)gq : (int)(gq - NB * NP);   // index within cloud
    int b  = gi >> 11;                                    // /NP
    int im = gi & (NP - 1);
    const float* home = (predHome ? pred : gt) + (size_t)b * NP * 3;

    float qx = home[3 * im], qy = home[3 * im + 1], qz = home[3 * im + 2];
    float qq = dot_rn(qx, qy, qz, qx, qy, qz);            // == sHome[im].w bitwise

    // --- merge 8x10 -> sorted top-16 (insert sequence identical; skipped
    //     inserts are provable no-ops: chain16(k, x) with x >= k[15] keeps k) ---
    unsigned k16[KN];
    #pragma unroll
    for (int s = 0; s < KW; ++s) k16[s] = kbuf_g[(size_t)(s * 8 + 0) * NQ + gq];
    #pragma unroll
    for (int s = KW; s < KN; ++s) k16[s] = 0x7F800000u | (unsigned)s;  // seeds (> any real)
    for (int w = 1; w < 8; ++w) {
        #pragma unroll
        for (int s = 0; s < KW; ++s) {
            unsigned kk = kbuf_g[(size_t)(s * 8 + w) * NQ + gq];
            if (__any(kk < k16[KN - 1])) chain16(k16, kk);
        }
    }
    float minv = fminf(fminf(fminf(mbuf_g[0 * NQ + gq], mbuf_g[1 * NQ + gq]),
                             fminf(mbuf_g[2 * NQ + gq], mbuf_g[3 * NQ + gq])),
                       fminf(fminf(mbuf_g[4 * NQ + gq], mbuf_g[5 * NQ + gq]),
                             fminf(mbuf_g[6 * NQ + gq], mbuf_g[7 * NQ + gq])));

    // --- violation detect: slice may hide a top-16 member iff its 10th-best
    //     < pool 16th. Exact repair (recompute from global, bit-identical). ---
    unsigned flags = 0;
    #pragma unroll
    for (int w = 0; w < 8; ++w)
        flags |= (kbuf_g[(size_t)((KW - 1) * 8 + w) * NQ + gq] < k16[KN - 1]) ? (1u << w) : 0u;

    if (__any(flags != 0)) {                 // ~0.07 expected events per LAUNCH
        #pragma unroll
        for (int s = 0; s < KN; ++s)
            k16[s] = flags ? (0x7F800000u | (unsigned)s) : k16[s];   // reinit flagged lanes
        for (int w = 0; w < 8; ++w) {
            #pragma unroll
            for (int s = 0; s < KW; ++s) {
                unsigned kk = kbuf_g[(size_t)(s * 8 + w) * NQ + gq];
                bool use = (flags != 0) && !((flags >> w) & 1);
                chain16(k16, use ? kk : 0xFFFFFFFFu);          // inf = no-op
            }
        }
        for (int w = 0; w < 8; ++w) {
            if (__any((flags >> w) & 1)) {
                bool actw = ((flags >> w) & 1) != 0;
                for (int t = 0; t < NP / 8; ++t) {
                    int jj = (t << 3) | w;
                    float hx = home[3 * jj], hy = home[3 * jj + 1], hz = home[3 * jj + 2];
                    float hw = dot_rn(hx, hy, hz, hx, hy, hz);
                    float dotj = dot_rn(qx, qy, qz, hx, hy, hz);
                    float d2 = __fsub_rn(__fadd_rn(qq, hw), __fmul_rn(2.f, dotj));
                    unsigned key = (__float_as_uint(d2) & 0xFFFFF800u) | (unsigned)jj;
                    chain16(k16, actw ? key : 0xFFFFFFFFu);
                }
            }
        }
    }

    // --- repulsion: k16 sorted ascending, slot 0 = self (d2=0) -> slots 1..4 ---
    float rep = 0.0f;
    if (predHome) {
        #pragma unroll
        for (int r = 1; r <= 4; ++r) {
            float d2 = __uint_as_float(k16[r] & 0xFFFFF800u);
            float dd = sqrtf(fmaxf(d2, 1e-12f));
            rep += fmaxf(0.02f - dd, 0.0f);
        }
    }

    // --- covariance over the 16-NN: gather from global (values bit-identical
    //     to kernel A's staging; same summation order) ---
    float sx = 0.f, sy = 0.f, sz = 0.f;
    #pragma unroll
    for (int s = 0; s < KN; ++s) {
        const float* hp = home + 3 * (size_t)(k16[s] & 0x7FFu);
        sx += hp[0]; sy += hp[1]; sz += hp[2];
    }
    float mx = sx * (1.0f / KN), my = sy * (1.0f / KN), mz = sz * (1.0f / KN);
    float cxx = 0.f, cxy = 0.f, cxz = 0.f, cyy = 0.f, cyz = 0.f, czz = 0.f;
    #pragma unroll
    for (int s = 0; s < KN; ++s) {
        const float* hp = home + 3 * (size_t)(k16[s] & 0x7FFu);
        float ax = hp[0] - mx;
        float ay = hp[1] - my;
        float az = hp[2] - mz;
        cxx += ax * ax; cxy += ax * ay; cxz += ax * az;
        cyy += ay * ay; cyz += ay * az; czz += az * az;
    }
    cxx *= (1.f / KN); cxy *= (1.f / KN); cxz *= (1.f / KN);
    cyy *= (1.f / KN); cyz *= (1.f / KN); czz *= (1.f / KN);

    // --- normal via faithful ssyevd emulation (register-resident) ---
    float nx, ny, nz;
    ssyevd3_evec0(cxx, cxy, cxz, cyy, cyz, czz, &nx, &ny, &nz);

    normals[gq * 3 + 0] = nx;     // [0..16384) = nP, [16384..32768) = nG
    normals[gq * 3 + 1] = ny;
    normals[gq * 3 + 2] = nz;

    double part = (double)minv * (1.0 / (NB * NP))
                + (double)rep  * (0.1 / (NB * NP * 4));

    #pragma unroll
    for (int off = 32; off > 0; off >>= 1) part += __shfl_down(part, off);
    if (lane == 0) wsum[wave] = part;
    __syncthreads();
    if (tid == 0) {
        double t = 0.0;
        #pragma unroll
        for (int w = 0; w < 8; ++w) t += wsum[w];
        cdpart[blockIdx.x] = t;
    }
}

// ---------------------------------------------------------------------------
// Finalize: 1 block x 1024 threads. Phase A: normal-dot with the EXACT
// per-thread fp32 order of the proven dot_kernel (vt = tid, stride 1024).
// Phase B: reduce 64 cdpart doubles + dot partials, write out.
__global__ __launch_bounds__(1024) void fin_kernel(
    const float* __restrict__ normals, const double* __restrict__ cdpart,
    float* __restrict__ out)
{
    __shared__ double wc[16], wd[16];
    int tid = threadIdx.x;
    int wave = tid >> 6, lane = tid & 63;
    const float* nP = normals;
    const float* nG = normals + (size_t)NB * NP * 3;

    float s = 0.f;
    for (int i = tid; i < NB * NP; i += 1024)
        s += nP[3 * i] * nG[3 * i] + nP[3 * i + 1] * nG[3 * i + 1] + nP[3 * i + 2] * nG[3 * i + 2];
    double d = (double)s;

    double c = (tid < 64) ? cdpart[tid] : 0.0;

    #pragma unroll
    for (int off = 32; off > 0; off >>= 1) {
        c += __shfl_down(c, off);
        d += __shfl_down(d, off);
    }
    if (lane == 0) { wc[wave] = c; wd[wave] = d; }
    __syncthreads();
    if (tid == 0) {
        double a = 0.0, t = 0.0;
        #pragma unroll
        for (int w = 0; w < 16; ++w) { a += wc[w]; t += wd[w]; }
        out[0] = (float)(a - t * (0.01 / (NB * NP)) + 0.01);
    }
}

// ---------------------------------------------------------------------------
extern "C" void kernel_launch(void* const* d_in, const int* in_sizes, int n_in,
                              void* d_out, int out_size, void* d_ws, size_t ws_size,
                              hipStream_t stream)
{
    const float* pred = (const float*)d_in[0];
    const float* gt   = (const float*)d_in[1];

    // ws layout: normals (32768*3*4 = 384KB) | cdpart (64 f64 = 512B, padded) |
    //            mbuf_g (32768*8*4 = 1MB) | kbuf_g (32768*80*4 = 10.5MB).
    // Total ~11.9MB. No memset: every slot written before read (stream order).
    char* base = (char*)d_ws;
    float*    normals = (float*)base;
    double*   cdpart  = (double*)(base + (size_t)NQ * 3 * 4);
    float*    mbuf_g  = (float*)(base + (size_t)NQ * 3 * 4 + 4096);
    unsigned* kbuf_g  = (unsigned*)(base + (size_t)NQ * 3 * 4 + 4096 + (size_t)NQ * 8 * 4);

    scan_kernel<<<dim3(NB * 32 * 2), dim3(512), 0, stream>>>(pred, gt, kbuf_g, mbuf_g);
    tail_kernel<<<dim3(64), dim3(512), 0, stream>>>(pred, gt, kbuf_g, mbuf_g, normals, cdpart);
    fin_kernel<<<dim3(1), dim3(1024), 0, stream>>>(normals, cdpart, (float*)d_out);
}

// Round 8
// 194.261 us; speedup vs baseline: 1.0760x; 1.0760x over previous
//
#include <hip/hip_runtime.h>

// CombinedLoss: chamfer(pred,gt) + 0.1*repulsion(pred,k=4) + 0.01*(1 - mean(n_pred . n_gt))
// B=8, N=2048, fp32 in, fp32 scalar out.
// Normals match np.linalg.eigh (LAPACK ssyevd) signs point-by-point via faithful
// fp32 ssytd2+ssteqr+sormtr emulation (R3-R7: absmax 0.0).
// R8: branchless sorted-chain top-10 per wave-slice, exact top-16 via 8x10 pool
// merge + violation-detect + rare rescan fallback.
// R9: eigensolver state in named registers (cndmask dynamic indexing).
// R13: masked tail REGRESSED (exec-masked lanes still consume issue slots).
// R14: fused tail at 0.5 waves/SIMD ~71us latency-exposed; 1-block fin = ~46us (1 CU!).
// R15: tail amputated to own kernel: 89.6us, VALUBusy 5.9%, Occ 2.7% ->
// LATENCY-BOUND (64 blocks on 64 CUs, serial global loads + dependent chains).
// R16: (a) tail at 32 blocks x 1024 thr = 16 waves/block = 4 waves/SIMD
// (launch_bounds(1024,4) caps VGPR<=128) -> 2x deeper latency interleave;
// (b) merge double-buffers 10-key batches in REGISTERS (w-loop unrolled,
// constant indices) - load latency pipelined behind chain16 VALU; slot-9
// "tenth" keys kept in regs (8 fewer loads). Insert sequence unchanged.
// (c) dot restored to 16-block kernel (R10-proven fp32 order) + 1-wave fin
// (the 1-block fused fin was a hidden ~46us on one CU). 4 launches (~2us each).

#define NB 8
#define NP 2048
#define KW 10     // per-slice kept keys
#define KN 16
#define NQ (2 * NB * NP)   // 32768 queries (both clouds)

// ---------------- LAPACK helpers (fp32, faithful — DO NOT TOUCH) ----------------

__device__ __forceinline__ float f_slapy2(float x, float y) {
    float xa = fabsf(x), ya = fabsf(y);
    float w = fmaxf(xa, ya), zm = fminf(xa, ya);
    if (zm == 0.f) return w;
    float q = zm / w;
    return w * sqrtf(1.f + q * q);
}

// LAPACK >=3.10 slartg convention: c >= 0 always.
__device__ __forceinline__ void f_slartg(float f, float g, float* cs, float* sn, float* r) {
    if (g == 0.f) { *cs = 1.f; *sn = 0.f; *r = f; }
    else if (f == 0.f) { *cs = 0.f; *sn = copysignf(1.f, g); *r = fabsf(g); }
    else {
        float d = sqrtf(__fadd_rn(__fmul_rn(f, f), __fmul_rn(g, g)));
        *cs = fabsf(f) / d;
        *r  = copysignf(d, f);
        *sn = g / *r;
    }
}

__device__ void f_slaev2(float a, float b, float c,
                         float* rt1, float* rt2, float* cs1, float* sn1) {
    float sm = a + c;
    float df = a - c;
    float adf = fabsf(df);
    float tb = b + b;
    float ab = fabsf(tb);
    float acmx, acmn;
    if (fabsf(a) > fabsf(c)) { acmx = a; acmn = c; } else { acmx = c; acmn = a; }
    float rt;
    if (adf > ab)      { float q = ab / adf; rt = adf * sqrtf(1.f + q * q); }
    else if (adf < ab) { float q = adf / ab; rt = ab * sqrtf(1.f + q * q); }
    else               rt = ab * sqrtf(2.f);
    int sgn1;
    if (sm < 0.f) {
        *rt1 = 0.5f * (sm - rt); sgn1 = -1;
        *rt2 = (acmx / *rt1) * acmn - (b / *rt1) * b;
    } else if (sm > 0.f) {
        *rt1 = 0.5f * (sm + rt); sgn1 = 1;
        *rt2 = (acmx / *rt1) * acmn - (b / *rt1) * b;
    } else {
        *rt1 = 0.5f * rt; *rt2 = -0.5f * rt; sgn1 = 1;
    }
    float cs; int sgn2;
    if (df >= 0.f) { cs = df + rt; sgn2 = 1; }
    else           { cs = df - rt; sgn2 = -1; }
    float acs = fabsf(cs);
    if (acs > ab) {
        float ct = -tb / cs;
        *sn1 = 1.f / sqrtf(1.f + ct * ct);
        *cs1 = ct * *sn1;
    } else {
        if (ab == 0.f) { *cs1 = 1.f; *sn1 = 0.f; }
        else {
            float tn = -cs / tb;
            *cs1 = 1.f / sqrtf(1.f + tn * tn);
            *sn1 = tn * *cs1;
        }
    }
    if (sgn1 == sgn2) { float tn = *cs1; *cs1 = -*sn1; *sn1 = tn; }
}

// --------- register-resident dynamic indexing (R9: replaces scratch arrays) ---------
// Selection only — bit-exact with array loads/stores; compiles to v_cndmask, no memory.

__device__ __forceinline__ float get3(float a, float b, float c, int i) {
    return i == 0 ? a : (i == 1 ? b : c);
}
__device__ __forceinline__ void set3(float& a, float& b, float& c, int i, float v) {
    a = (i == 0) ? v : a;
    b = (i == 1) ? v : b;
    c = (i == 2) ? v : c;
}
__device__ __forceinline__ float get2(float a, float b, int i) { return i == 0 ? a : b; }
__device__ __forceinline__ void set2(float& a, float& b, int i, float v) {
    a = (i == 0) ? v : a;
    b = (i == 1) ? v : b;
}

#define DGET(i)    get3(dd0, dd1, dd2, (i))
#define DSET(i, v) set3(dd0, dd1, dd2, (i), (v))
#define EGET(i)    get2(ee0, ee1, (i))
#define ESET(i, v) set2(ee0, ee1, (i), (v))
#define ZGET(r, c)    get3(z##r##0, z##r##1, z##r##2, (c))
#define ZSET(r, c, v) set3(z##r##0, z##r##1, z##r##2, (c), (v))
// Two-column Givens update: cols (ca,cb) <- (cc*ca - ss*cb, ss*ca + cc*cb), all 3 rows.
#define ZROT(r, ca, cb, cc, ss) { float zt_ = ZGET(r, (ca)); float zb_ = ZGET(r, (cb)); \
    ZSET(r, (ca), (cc) * zt_ - (ss) * zb_); ZSET(r, (cb), (ss) * zt_ + (cc) * zb_); }
#define ZROT3(ca, cb, cc, ss) { ZROT(0, (ca), (cb), (cc), (ss)) ZROT(1, (ca), (cb), (cc), (ss)) ZROT(2, (ca), (cb), (cc), (ss)) }

// fp32 ssyevd for a 3x3 symmetric matrix (lower triangle given), returns
// eigenvector of the SMALLEST eigenvalue, with LAPACK's sign convention.
__device__ void ssyevd3_evec0(float a00, float a10, float a20,
                              float a11, float a21, float a22,
                              float* ox, float* oy, float* oz) {
    // ---- ssytd2('L') ----
    float dd0, dd1, dd2, ee0, ee1;
    float tau = 0.f, v2 = 0.f;
    float xnorm = fabsf(a20);
    if (xnorm == 0.f) {
        tau = 0.f;
        dd0 = a00; dd1 = a11; dd2 = a22; ee0 = a10; ee1 = a21;
    } else {
        float beta = -copysignf(f_slapy2(a10, xnorm), a10);
        tau = (beta - a10) / beta;
        float inv = 1.f / (a10 - beta);
        v2 = a20 * inv;
        float x1 = tau * (a11 + a21 * v2);
        float x2 = tau * (a21 + a22 * v2);
        float alpha = -0.5f * tau * (x1 + x2 * v2);
        float w1 = x1 + alpha;
        float w2 = x2 + alpha * v2;
        float b11 = a11 - 2.f * w1;
        float b21 = a21 - v2 * w1 - w2;
        float b22 = a22 - 2.f * (v2 * w2);
        dd0 = a00; dd1 = b11; dd2 = b22; ee0 = beta; ee1 = b21;
    }
    // ---- ssteqr('I', n=3) ----
    const float eps    = 5.9604645e-08f;
    const float eps2   = eps * eps;
    const float safmin = 1.1754944e-38f;
    const float ssfmax = sqrtf(1.f / safmin) / 3.f;
    const float ssfmin = sqrtf(safmin) / eps2;
    const int n = 3, nmaxit = 90;
    float z00 = 1.f, z01 = 0.f, z02 = 0.f;
    float z10 = 0.f, z11 = 1.f, z12 = 0.f;
    float z20 = 0.f, z21 = 0.f, z22 = 1.f;
    int jtot = 0;
    int l1 = 1;

    while (true) {
        if (l1 > n) break;
        if (l1 > 1) ESET(l1 - 2, 0.f);
        int m = n;
        {   // for (mi = l1; mi <= n-1; ++mi) with first-hit break
            bool found = false;
            #pragma unroll
            for (int mi = 1; mi <= 2; ++mi) {
                if (!found && mi >= l1) {
                    float tst = fabsf(EGET(mi - 1));
                    if (tst == 0.f) { m = mi; found = true; }
                    else if (tst <= (sqrtf(fabsf(DGET(mi - 1))) * sqrtf(fabsf(DGET(mi)))) * eps) {
                        ESET(mi - 1, 0.f); m = mi; found = true;
                    }
                }
            }
        }
        int l = l1, lsv = l, lend = m, lendsv = lend;
        l1 = m + 1;
        if (lend == l) continue;

        float anorm = 0.f;
        #pragma unroll
        for (int i = 1; i <= 3; ++i)
            if (i >= l && i <= lend) anorm = fmaxf(anorm, fabsf(DGET(i - 1)));
        #pragma unroll
        for (int i = 1; i <= 2; ++i)
            if (i >= l && i <= lend - 1) anorm = fmaxf(anorm, fabsf(EGET(i - 1)));
        int iscale = 0; float sclto = 1.f;
        if (anorm == 0.f) continue;
        if (anorm > ssfmax) { iscale = 1; sclto = ssfmax; }
        else if (anorm < ssfmin) { iscale = 2; sclto = ssfmin; }
        if (iscale) {
            float mul = sclto / anorm;
            #pragma unroll
            for (int i = 1; i <= 3; ++i)
                if (i >= l && i <= lend) DSET(i - 1, DGET(i - 1) * mul);
            #pragma unroll
            for (int i = 1; i <= 2; ++i)
                if (i >= l && i <= lend - 1) ESET(i - 1, EGET(i - 1) * mul);
        }
        if (fabsf(DGET(lend - 1)) < fabsf(DGET(l - 1))) { lend = lsv; l = lendsv; }

        if (lend > l) {
            // QL
            while (true) {
                int mq = lend;
                if (l != lend) {
                    bool found = false;
                    #pragma unroll
                    for (int i = 1; i <= 2; ++i) {
                        if (!found && i >= l && i <= lend - 1) {
                            float ei = EGET(i - 1);
                            float tst = ei * ei;
                            if (tst <= (eps2 * fabsf(DGET(i - 1))) * fabsf(DGET(i)) + safmin) { mq = i; found = true; }
                        }
                    }
                }
                if (mq < lend) ESET(mq - 1, 0.f);
                float p = DGET(l - 1);
                if (mq == l) { DSET(l - 1, p); l = l + 1; if (l <= lend) continue; break; }
                if (mq == l + 1) {
                    float rt1, rt2, c, s;
                    f_slaev2(DGET(l - 1), EGET(l - 1), DGET(l), &rt1, &rt2, &c, &s);
                    ZROT3(l, l - 1, c, s);
                    DSET(l - 1, rt1); DSET(l, rt2); ESET(l - 1, 0.f);
                    l += 2; if (l <= lend) continue; break;
                }
                if (jtot == nmaxit) break;
                jtot++;
                float g = (DGET(l) - p) / (2.f * EGET(l - 1));
                float r = f_slapy2(g, 1.f);
                g = DGET(mq - 1) - p + EGET(l - 1) / (g + copysignf(r, g));
                float s = 1.f, c = 1.f; p = 0.f;
                float cw0 = 0.f, cw1 = 0.f, sw0 = 0.f, sw1 = 0.f;
                // for (i = mq-1; i >= l; --i)
                #pragma unroll
                for (int i = 2; i >= 1; --i) {
                    if (i <= mq - 1 && i >= l) {
                        float f = s * EGET(i - 1);
                        float b = c * EGET(i - 1);
                        f_slartg(g, f, &c, &s, &r);
                        if (i != mq - 1) ESET(i, r);
                        g = DGET(i) - p;
                        r = (DGET(i - 1) - g) * s + 2.f * c * b;
                        p = s * r;
                        DSET(i, g + p);
                        g = c * r - b;
                        set2(cw0, cw1, i - l, c);
                        set2(sw0, sw1, i - l, -s);
                    }
                }
                // for (j = mq-l; j >= 1; --j)
                #pragma unroll
                for (int j = 2; j >= 1; --j) {
                    if (j <= mq - l) {
                        float cj = get2(cw0, cw1, j - 1), sj = get2(sw0, sw1, j - 1);
                        int c0 = l - 1 + (j - 1);
                        ZROT3(c0 + 1, c0, cj, sj);
                    }
                }
                DSET(l - 1, DGET(l - 1) - p);
                ESET(l - 1, g);
            }
        } else {
            // QR
            while (true) {
                int mq = lend;
                if (l != lend) {
                    bool found = false;
                    // for (i = l; i >= lend+1; --i)
                    #pragma unroll
                    for (int i = 3; i >= 2; --i) {
                        if (!found && i <= l && i >= lend + 1) {
                            float ei = EGET(i - 2);
                            float tst = ei * ei;
                            if (tst <= (eps2 * fabsf(DGET(i - 1))) * fabsf(DGET(i - 2)) + safmin) { mq = i; found = true; }
                        }
                    }
                }
                if (mq > lend) ESET(mq - 2, 0.f);
                float p = DGET(l - 1);
                if (mq == l) { DSET(l - 1, p); l = l - 1; if (l >= lend) continue; break; }
                if (mq == l - 1) {
                    float rt1, rt2, c, s;
                    f_slaev2(DGET(l - 2), EGET(l - 2), DGET(l - 1), &rt1, &rt2, &c, &s);
                    ZROT3(l - 1, l - 2, c, s);
                    DSET(l - 2, rt1); DSET(l - 1, rt2); ESET(l - 2, 0.f);
                    l -= 2; if (l >= lend) continue; break;
                }
                if (jtot == nmaxit) break;
                jtot++;
                float g = (DGET(l - 2) - p) / (2.f * EGET(l - 2));
                float r = f_slapy2(g, 1.f);
                g = DGET(mq - 1) - p + EGET(l - 2) / (g + copysignf(r, g));
                float s = 1.f, c = 1.f; p = 0.f;
                float cw0 = 0.f, cw1 = 0.f, sw0 = 0.f, sw1 = 0.f;
                // for (i = mq; i <= l-1; ++i)
                #pragma unroll
                for (int i = 1; i <= 2; ++i) {
                    if (i >= mq && i <= l - 1) {
                        float f = s * EGET(i - 1);
                        float b = c * EGET(i - 1);
                        f_slartg(g, f, &c, &s, &r);
                        if (i != mq) ESET(i - 2, r);
                        g = DGET(i - 1) - p;
                        r = (DGET(i) - g) * s + 2.f * c * b;
                        p = s * r;
                        DSET(i - 1, g + p);
                        g = c * r - b;
                        set2(cw0, cw1, i - mq, c);
                        set2(sw0, sw1, i - mq, s);
                    }
                }
                // for (j = 1; j <= l-mq; ++j)
                #pragma unroll
                for (int j = 1; j <= 2; ++j) {
                    if (j <= l - mq) {
                        float cj = get2(cw0, cw1, j - 1), sj = get2(sw0, sw1, j - 1);
                        int c0 = mq - 1 + (j - 1);
                        ZROT3(c0 + 1, c0, cj, sj);
                    }
                }
                DSET(l - 1, DGET(l - 1) - p);
                ESET(l - 2, g);
            }
        }
        if (iscale) {
            float mul = anorm / sclto;
            #pragma unroll
            for (int i = 1; i <= 3; ++i)
                if (i >= lsv && i <= lendsv) DSET(i - 1, DGET(i - 1) * mul);
            #pragma unroll
            for (int i = 1; i <= 2; ++i)
                if (i >= lsv && i <= lendsv - 1) ESET(i - 1, EGET(i - 1) * mul);
        }
        if (jtot >= nmaxit) break;
    }

    // sort ascending (column swaps — no sign change)
    #pragma unroll
    for (int ii = 2; ii <= 3; ++ii) {
        int i = ii - 1, k = i;
        float p = DGET(i - 1);
        #pragma unroll
        for (int j = ii; j <= 3; ++j)
            if (DGET(j - 1) < p) { k = j; p = DGET(j - 1); }
        if (k != i) {
            DSET(k - 1, DGET(i - 1)); DSET(i - 1, p);
            { float t0 = ZGET(0, i - 1); ZSET(0, i - 1, ZGET(0, k - 1)); ZSET(0, k - 1, t0); }
            { float t1 = ZGET(1, i - 1); ZSET(1, i - 1, ZGET(1, k - 1)); ZSET(1, k - 1, t1); }
            { float t2 = ZGET(2, i - 1); ZSET(2, i - 1, ZGET(2, k - 1)); ZSET(2, k - 1, t2); }
        }
    }
    // sormtr('L','L','N')
    float r0 = z00, r1 = z10, r2 = z20;
    if (tau != 0.f) {
        float sum = r1 + v2 * r2;
        r1 -= tau * sum;
        r2 -= tau * (v2 * sum);
    }
    *ox = r0; *oy = r1; *oz = r2;
}

// ---------------- common ----------------

__device__ __forceinline__ float dot_rn(float ax, float ay, float az,
                                        float bx, float by, float bz) {
    return __fadd_rn(__fadd_rn(__fmul_rn(ax, bx), __fmul_rn(ay, by)), __fmul_rn(az, bz));
}

// Branchless sorted-chain inserts: keys ascending; drops the largest.
__device__ __forceinline__ void chain10(unsigned k[KW], unsigned x) {
    unsigned t = x;
    #pragma unroll
    for (int s = 0; s < KW; ++s) {
        unsigned lo = k[s] < t ? k[s] : t;
        unsigned hi = k[s] < t ? t : k[s];
        k[s] = lo; t = hi;
    }
}
__device__ __forceinline__ void chain16(unsigned k[KN], unsigned x) {
    unsigned t = x;
    #pragma unroll
    for (int s = 0; s < KN; ++s) {
        unsigned lo = k[s] < t ? k[s] : t;
        unsigned hi = k[s] < t ? t : k[s];
        k[s] = lo; t = hi;
    }
}

// ---------------- Kernel A: scan only ----------------
// 512 blocks x 512 threads (8 waves), 2 blocks/CU (64KB LDS). Wave w scans
// interleaved slice j=8t+w keeping branchless sorted top-10 per lane-query +
// chamfer partial min, then stores keys+min straight to global (coalesced per
// (s,wave): 64 consecutive u32) and exits. No tail, no second barrier.
__global__ __launch_bounds__(512, 4) void scan_kernel(
    const float* __restrict__ pred, const float* __restrict__ gt,
    unsigned* __restrict__ kbuf_g, float* __restrict__ mbuf_g)
{
    __shared__ float4 sHome[NP];            // (x,y,z,|p|^2)  32 KB
    __shared__ float4 sOther[NP];           // (x,y,z,0)      32 KB

    int bi = blockIdx.x;
    bool predHome = bi < NB * 32;
    int lb = predHome ? bi : bi - NB * 32;
    int b = lb >> 5;
    int tile = lb & 31;
    int tid  = threadIdx.x;
    int wave = tid >> 6;
    int lane = tid & 63;

    const float* home  = (predHome ? pred : gt) + (size_t)b * NP * 3;
    const float* other = (predHome ? gt : pred) + (size_t)b * NP * 3;

    for (int t = tid; t < NP; t += 512) {
        float hx = home[3 * t], hy = home[3 * t + 1], hz = home[3 * t + 2];
        sHome[t] = make_float4(hx, hy, hz, dot_rn(hx, hy, hz, hx, hy, hz));
        float ox = other[3 * t], oy = other[3 * t + 1], oz = other[3 * t + 2];
        sOther[t] = make_float4(ox, oy, oz, 0.f);
    }
    __syncthreads();

    int im = tile * 64 + lane;              // original index of this lane's query
    float4 qv = sHome[im];
    float qx = qv.x, qy = qv.y, qz = qv.z, qq = qv.w;

    unsigned keys[KW];
    #pragma unroll
    for (int s = 0; s < KW; ++s) keys[s] = 0x7F800000u | (unsigned)s;  // sorted inf seeds

    float minv = 1e30f;

    for (int t = 0; t < NP / 8; ++t) {
        int jj = (t << 3) | wave;
        float4 h = sHome[jj];                                  // broadcast b128
        float dotj = dot_rn(qx, qy, qz, h.x, h.y, h.z);
        float d2 = __fsub_rn(__fadd_rn(qq, h.w), __fmul_rn(2.f, dotj));
        chain10(keys, (__float_as_uint(d2) & 0xFFFFF800u) | (unsigned)jj);
        float4 o = sOther[jj];                                 // broadcast b128
        float ex = qx - o.x, ey = qy - o.y, ez = qz - o.z;
        minv = fminf(minv, fmaf(ex, ex, fmaf(ey, ey, ez * ez)));
    }

    // store sorted top-10 + chamfer min straight to global (coalesced per (s,wave))
    size_t gq = (size_t)(predHome ? 0 : NB * NP) + (size_t)b * NP + im;
    #pragma unroll
    for (int s = 0; s < KW; ++s)
        kbuf_g[(size_t)(s * 8 + wave) * NQ + gq] = keys[s];
    mbuf_g[(size_t)wave * NQ + gq] = minv;
}

// ---------------- Kernel B: packed tail, deep wave stacking ----------------
// 32 blocks x 1024 threads = 512 waves, 16 waves/block -> 4 waves/SIMD resident
// (launch_bounds(1024,4) caps VGPR<=128). Lane = query gq. Merge 8x10 keys with
// double-buffered REGISTER prefetch (w-loop unrolled, constant idx): batch w+1
// loads issue while batch w chain16s run. Insert sequence identical to R9/R15
// (guarded skip is a provable no-op when kk >= k16[15]). tenth[w] (slot-9 keys)
// captured in regs during merge. Violation fallback recomputes from global
// (bit-identical fp32). Covariance gather from global (values bit-identical to
// scan's staging, same order). Eigensolver unchanged.
__global__ __launch_bounds__(1024, 4) void tail_kernel(
    const float* __restrict__ pred, const float* __restrict__ gt,
    const unsigned* __restrict__ kbuf_g, const float* __restrict__ mbuf_g,
    float* __restrict__ normals, double* __restrict__ cdpart)
{
    __shared__ double wsum[16];
    int tid = threadIdx.x;
    int wave = tid >> 6, lane = tid & 63;
    size_t gq = (size_t)blockIdx.x * 1024 + tid;

    bool predHome = gq < (size_t)(NB * NP);
    int gi = predHome ? (int)gq : (int)(gq - NB * NP);   // index within cloud
    int b  = gi >> 11;                                    // /NP
    int im = gi & (NP - 1);
    const float* home = (predHome ? pred : gt) + (size_t)b * NP * 3;

    float qx = home[3 * im], qy = home[3 * im + 1], qz = home[3 * im + 2];
    float qq = dot_rn(qx, qy, qz, qx, qy, qz);            // == sHome[im].w bitwise

    // --- merge 8x10 -> sorted top-16, register-double-buffered ---
    unsigned k16[KN];
    unsigned tenth[8];                                    // constant-indexed after unroll
    #pragma unroll
    for (int s = 0; s < KW; ++s) k16[s] = kbuf_g[(size_t)(s * 8 + 0) * NQ + gq];
    tenth[0] = k16[KW - 1];
    #pragma unroll
    for (int s = KW; s < KN; ++s) k16[s] = 0x7F800000u | (unsigned)s;  // seeds (> any real)

    unsigned kc[KW], kn[KW];
    #pragma unroll
    for (int s = 0; s < KW; ++s) kc[s] = kbuf_g[(size_t)(s * 8 + 1) * NQ + gq];
    #pragma unroll
    for (int w = 1; w < 8; ++w) {
        if (w < 7) {
            #pragma unroll
            for (int s = 0; s < KW; ++s) kn[s] = kbuf_g[(size_t)(s * 8 + (w + 1)) * NQ + gq];
        }
        tenth[w] = kc[KW - 1];
        #pragma unroll
        for (int s = 0; s < KW; ++s) {
            unsigned kk = kc[s];
            if (__any(kk < k16[KN - 1])) chain16(k16, kk);  // skip = provable no-op
        }
        if (w < 7) {
            #pragma unroll
            for (int s = 0; s < KW; ++s) kc[s] = kn[s];
        }
    }
    float minv = fminf(fminf(fminf(mbuf_g[0 * NQ + gq], mbuf_g[1 * NQ + gq]),
                             fminf(mbuf_g[2 * NQ + gq], mbuf_g[3 * NQ + gq])),
                       fminf(fminf(mbuf_g[4 * NQ + gq], mbuf_g[5 * NQ + gq]),
                             fminf(mbuf_g[6 * NQ + gq], mbuf_g[7 * NQ + gq])));

    // --- violation detect from register-held tenth keys ---
    unsigned flags = 0;
    #pragma unroll
    for (int w = 0; w < 8; ++w)
        flags |= (tenth[w] < k16[KN - 1]) ? (1u << w) : 0u;

    if (__any(flags != 0)) {                 // ~0.07 expected events per LAUNCH
        #pragma unroll
        for (int s = 0; s < KN; ++s)
            k16[s] = flags ? (0x7F800000u | (unsigned)s) : k16[s];   // reinit flagged lanes
        for (int w = 0; w < 8; ++w) {
            #pragma unroll
            for (int s = 0; s < KW; ++s) {
                unsigned kk = kbuf_g[(size_t)(s * 8 + w) * NQ + gq];
                bool use = (flags != 0) && !((flags >> w) & 1);
                chain16(k16, use ? kk : 0xFFFFFFFFu);          // inf = no-op
            }
        }
        for (int w = 0; w < 8; ++w) {
            if (__any((flags >> w) & 1)) {
                bool actw = ((flags >> w) & 1) != 0;
                for (int t = 0; t < NP / 8; ++t) {
                    int jj = (t << 3) | w;
                    float hx = home[3 * jj], hy = home[3 * jj + 1], hz = home[3 * jj + 2];
                    float hw = dot_rn(hx, hy, hz, hx, hy, hz);
                    float dotj = dot_rn(qx, qy, qz, hx, hy, hz);
                    float d2 = __fsub_rn(__fadd_rn(qq, hw), __fmul_rn(2.f, dotj));
                    unsigned key = (__float_as_uint(d2) & 0xFFFFF800u) | (unsigned)jj;
                    chain16(k16, actw ? key : 0xFFFFFFFFu);
                }
            }
        }
    }

    // --- repulsion: k16 sorted ascending, slot 0 = self (d2=0) -> slots 1..4 ---
    float rep = 0.0f;
    if (predHome) {
        #pragma unroll
        for (int r = 1; r <= 4; ++r) {
            float d2 = __uint_as_float(k16[r] & 0xFFFFF800u);
            float dd = sqrtf(fmaxf(d2, 1e-12f));
            rep += fmaxf(0.02f - dd, 0.0f);
        }
    }

    // --- covariance over the 16-NN: gather from global (values bit-identical
    //     to kernel A's staging; same summation order; loads independent) ---
    float sx = 0.f, sy = 0.f, sz = 0.f;
    #pragma unroll
    for (int s = 0; s < KN; ++s) {
        const float* hp = home + 3 * (size_t)(k16[s] & 0x7FFu);
        sx += hp[0]; sy += hp[1]; sz += hp[2];
    }
    float mx = sx * (1.0f / KN), my = sy * (1.0f / KN), mz = sz * (1.0f / KN);
    float cxx = 0.f, cxy = 0.f, cxz = 0.f, cyy = 0.f, cyz = 0.f, czz = 0.f;
    #pragma unroll
    for (int s = 0; s < KN; ++s) {
        const float* hp = home + 3 * (size_t)(k16[s] & 0x7FFu);
        float ax = hp[0] - mx;
        float ay = hp[1] - my;
        float az = hp[2] - mz;
        cxx += ax * ax; cxy += ax * ay; cxz += ax * az;
        cyy += ay * ay; cyz += ay * az; czz += az * az;
    }
    cxx *= (1.f / KN); cxy *= (1.f / KN); cxz *= (1.f / KN);
    cyy *= (1.f / KN); cyz *= (1.f / KN); czz *= (1.f / KN);

    // --- normal via faithful ssyevd emulation (register-resident) ---
    float nx, ny, nz;
    ssyevd3_evec0(cxx, cxy, cxz, cyy, cyz, czz, &nx, &ny, &nz);

    normals[gq * 3 + 0] = nx;     // [0..16384) = nP, [16384..32768) = nG
    normals[gq * 3 + 1] = ny;
    normals[gq * 3 + 2] = nz;

    double part = (double)minv * (1.0 / (NB * NP))
                + (double)rep  * (0.1 / (NB * NP * 4));

    #pragma unroll
    for (int off = 32; off > 0; off >>= 1) part += __shfl_down(part, off);
    if (lane == 0) wsum[wave] = part;
    __syncthreads();
    if (tid == 0) {
        double t = 0.0;
        #pragma unroll
        for (int w = 0; w < 16; ++w) t += wsum[w];
        cdpart[blockIdx.x] = t;
    }
}

// ---------------------------------------------------------------------------
// Normal-dot partials: 16 blocks x 64 threads = the R10-proven per-thread fp32
// summation order (vt = bid*64+tid, stride 1024); plain-stores dotpart[bid].
__global__ __launch_bounds__(64) void dot_kernel(
    const float* __restrict__ normals, double* __restrict__ dotpart)
{
    const float* nP = normals;
    const float* nG = normals + (size_t)NB * NP * 3;
    int vt = blockIdx.x * 64 + threadIdx.x;   // 0..1023
    float s = 0.f;
    for (int i = vt; i < NB * NP; i += 1024)
        s += nP[3 * i] * nG[3 * i] + nP[3 * i + 1] * nG[3 * i + 1] + nP[3 * i + 2] * nG[3 * i + 2];
    double part = (double)s;
    #pragma unroll
    for (int off = 32; off > 0; off >>= 1) part += __shfl_down(part, off);
    if (threadIdx.x == 0) dotpart[blockIdx.x] = part;
}

// ---------------------------------------------------------------------------
// Micro-finalize: 1 wave. Reduce 32 cdpart + 16 dotpart doubles, write out.
__global__ __launch_bounds__(64) void fin_kernel(
    const double* __restrict__ cdpart, const double* __restrict__ dotpart,
    float* __restrict__ out)
{
    int tid = threadIdx.x;
    double c = (tid < 32) ? cdpart[tid] : 0.0;
    double d = (tid < 16) ? dotpart[tid] : 0.0;
    #pragma unroll
    for (int off = 32; off > 0; off >>= 1) {
        c += __shfl_down(c, off);
        d += __shfl_down(d, off);
    }
    if (tid == 0)
        out[0] = (float)(c - d * (0.01 / (NB * NP)) + 0.01);
}

// ---------------------------------------------------------------------------
extern "C" void kernel_launch(void* const* d_in, const int* in_sizes, int n_in,
                              void* d_out, int out_size, void* d_ws, size_t ws_size,
                              hipStream_t stream)
{
    const float* pred = (const float*)d_in[0];
    const float* gt   = (const float*)d_in[1];

    // ws layout: normals (384KB) | cdpart (32 f64) + dotpart (16 f64) in 4KB pad |
    //            mbuf_g (1MB) | kbuf_g (10.5MB). No memset: every slot written
    //            before read (stream order).
    char* base = (char*)d_ws;
    float*    normals = (float*)base;
    double*   cdpart  = (double*)(base + (size_t)NQ * 3 * 4);
    double*   dotpart = cdpart + 64;
    float*    mbuf_g  = (float*)(base + (size_t)NQ * 3 * 4 + 4096);
    unsigned* kbuf_g  = (unsigned*)(base + (size_t)NQ * 3 * 4 + 4096 + (size_t)NQ * 8 * 4);

    scan_kernel<<<dim3(NB * 32 * 2), dim3(512), 0, stream>>>(pred, gt, kbuf_g, mbuf_g);
    tail_kernel<<<dim3(32), dim3(1024), 0, stream>>>(pred, gt, kbuf_g, mbuf_g, normals, cdpart);
    dot_kernel<<<dim3(16), dim3(64), 0, stream>>>(normals, dotpart);
    fin_kernel<<<dim3(1), dim3(64), 0, stream>>>(cdpart, dotpart, (float*)d_out);
}

// Round 9
// 186.726 us; speedup vs baseline: 1.1194x; 1.0404x over previous
//
#include <hip/hip_runtime.h>

// CombinedLoss: chamfer(pred,gt) + 0.1*repulsion(pred,k=4) + 0.01*(1 - mean(n_pred . n_gt))
// B=8, N=2048, fp32 in, fp32 scalar out.
// Normals match np.linalg.eigh (LAPACK ssyevd) signs point-by-point via faithful
// fp32 ssytd2+ssteqr+sormtr emulation (R3-R7: absmax 0.0).
// R8: branchless sorted-chain top-10 per wave-slice + exact top-16 merge.
// R9: eigensolver state in named registers. R13: masked tail regressed (exec-mask
// lanes still cost issue slots). R15: tail amputated -> measured latency-bound.
// R16: tail 4 waves/SIMD on 32 CUs: 73us, but active-CU VALUBusy ~56% -> the
// mistake was USING ONLY 32/256 CUs; per-wave issue work V~24K cyc is large.
// R17: (a) tail spread across ALL 256 CUs: 256 blocks x 128 thr; wave0 = pred
// query i, wave1 = gt query i (same index). Per-SIMD load = 1 wave -> V+L once.
// (b) dot FUSED: wave1 stages its nG in LDS; wave0 dots vs register nP (fp32
// triple product, double combine; ~1e-12 on out vs 2.7e-4 threshold). Dot
// kernel, 384KB normals round-trip, and one launch+gap eliminated. 3 launches.

#define NB 8
#define NP 2048
#define KW 10     // per-slice kept keys
#define KN 16
#define NQ (2 * NB * NP)   // 32768 queries (both clouds)

// ---------------- LAPACK helpers (fp32, faithful — DO NOT TOUCH) ----------------

__device__ __forceinline__ float f_slapy2(float x, float y) {
    float xa = fabsf(x), ya = fabsf(y);
    float w = fmaxf(xa, ya), zm = fminf(xa, ya);
    if (zm == 0.f) return w;
    float q = zm / w;
    return w * sqrtf(1.f + q * q);
}

// LAPACK >=3.10 slartg convention: c >= 0 always.
__device__ __forceinline__ void f_slartg(float f, float g, float* cs, float* sn, float* r) {
    if (g == 0.f) { *cs = 1.f; *sn = 0.f; *r = f; }
    else if (f == 0.f) { *cs = 0.f; *sn = copysignf(1.f, g); *r = fabsf(g); }
    else {
        float d = sqrtf(__fadd_rn(__fmul_rn(f, f), __fmul_rn(g, g)));
        *cs = fabsf(f) / d;
        *r  = copysignf(d, f);
        *sn = g / *r;
    }
}

__device__ void f_slaev2(float a, float b, float c,
                         float* rt1, float* rt2, float* cs1, float* sn1) {
    float sm = a + c;
    float df = a - c;
    float adf = fabsf(df);
    float tb = b + b;
    float ab = fabsf(tb);
    float acmx, acmn;
    if (fabsf(a) > fabsf(c)) { acmx = a; acmn = c; } else { acmx = c; acmn = a; }
    float rt;
    if (adf > ab)      { float q = ab / adf; rt = adf * sqrtf(1.f + q * q); }
    else if (adf < ab) { float q = adf / ab; rt = ab * sqrtf(1.f + q * q); }
    else               rt = ab * sqrtf(2.f);
    int sgn1;
    if (sm < 0.f) {
        *rt1 = 0.5f * (sm - rt); sgn1 = -1;
        *rt2 = (acmx / *rt1) * acmn - (b / *rt1) * b;
    } else if (sm > 0.f) {
        *rt1 = 0.5f * (sm + rt); sgn1 = 1;
        *rt2 = (acmx / *rt1) * acmn - (b / *rt1) * b;
    } else {
        *rt1 = 0.5f * rt; *rt2 = -0.5f * rt; sgn1 = 1;
    }
    float cs; int sgn2;
    if (df >= 0.f) { cs = df + rt; sgn2 = 1; }
    else           { cs = df - rt; sgn2 = -1; }
    float acs = fabsf(cs);
    if (acs > ab) {
        float ct = -tb / cs;
        *sn1 = 1.f / sqrtf(1.f + ct * ct);
        *cs1 = ct * *sn1;
    } else {
        if (ab == 0.f) { *cs1 = 1.f; *sn1 = 0.f; }
        else {
            float tn = -cs / tb;
            *cs1 = 1.f / sqrtf(1.f + tn * tn);
            *sn1 = tn * *cs1;
        }
    }
    if (sgn1 == sgn2) { float tn = *cs1; *cs1 = -*sn1; *sn1 = tn; }
}

// --------- register-resident dynamic indexing (R9: replaces scratch arrays) ---------
// Selection only — bit-exact with array loads/stores; compiles to v_cndmask, no memory.

__device__ __forceinline__ float get3(float a, float b, float c, int i) {
    return i == 0 ? a : (i == 1 ? b : c);
}
__device__ __forceinline__ void set3(float& a, float& b, float& c, int i, float v) {
    a = (i == 0) ? v : a;
    b = (i == 1) ? v : b;
    c = (i == 2) ? v : c;
}
__device__ __forceinline__ float get2(float a, float b, int i) { return i == 0 ? a : b; }
__device__ __forceinline__ void set2(float& a, float& b, int i, float v) {
    a = (i == 0) ? v : a;
    b = (i == 1) ? v : b;
}

#define DGET(i)    get3(dd0, dd1, dd2, (i))
#define DSET(i, v) set3(dd0, dd1, dd2, (i), (v))
#define EGET(i)    get2(ee0, ee1, (i))
#define ESET(i, v) set2(ee0, ee1, (i), (v))
#define ZGET(r, c)    get3(z##r##0, z##r##1, z##r##2, (c))
#define ZSET(r, c, v) set3(z##r##0, z##r##1, z##r##2, (c), (v))
// Two-column Givens update: cols (ca,cb) <- (cc*ca - ss*cb, ss*ca + cc*cb), all 3 rows.
#define ZROT(r, ca, cb, cc, ss) { float zt_ = ZGET(r, (ca)); float zb_ = ZGET(r, (cb)); \
    ZSET(r, (ca), (cc) * zt_ - (ss) * zb_); ZSET(r, (cb), (ss) * zt_ + (cc) * zb_); }
#define ZROT3(ca, cb, cc, ss) { ZROT(0, (ca), (cb), (cc), (ss)) ZROT(1, (ca), (cb), (cc), (ss)) ZROT(2, (ca), (cb), (cc), (ss)) }

// fp32 ssyevd for a 3x3 symmetric matrix (lower triangle given), returns
// eigenvector of the SMALLEST eigenvalue, with LAPACK's sign convention.
__device__ void ssyevd3_evec0(float a00, float a10, float a20,
                              float a11, float a21, float a22,
                              float* ox, float* oy, float* oz) {
    // ---- ssytd2('L') ----
    float dd0, dd1, dd2, ee0, ee1;
    float tau = 0.f, v2 = 0.f;
    float xnorm = fabsf(a20);
    if (xnorm == 0.f) {
        tau = 0.f;
        dd0 = a00; dd1 = a11; dd2 = a22; ee0 = a10; ee1 = a21;
    } else {
        float beta = -copysignf(f_slapy2(a10, xnorm), a10);
        tau = (beta - a10) / beta;
        float inv = 1.f / (a10 - beta);
        v2 = a20 * inv;
        float x1 = tau * (a11 + a21 * v2);
        float x2 = tau * (a21 + a22 * v2);
        float alpha = -0.5f * tau * (x1 + x2 * v2);
        float w1 = x1 + alpha;
        float w2 = x2 + alpha * v2;
        float b11 = a11 - 2.f * w1;
        float b21 = a21 - v2 * w1 - w2;
        float b22 = a22 - 2.f * (v2 * w2);
        dd0 = a00; dd1 = b11; dd2 = b22; ee0 = beta; ee1 = b21;
    }
    // ---- ssteqr('I', n=3) ----
    const float eps    = 5.9604645e-08f;
    const float eps2   = eps * eps;
    const float safmin = 1.1754944e-38f;
    const float ssfmax = sqrtf(1.f / safmin) / 3.f;
    const float ssfmin = sqrtf(safmin) / eps2;
    const int n = 3, nmaxit = 90;
    float z00 = 1.f, z01 = 0.f, z02 = 0.f;
    float z10 = 0.f, z11 = 1.f, z12 = 0.f;
    float z20 = 0.f, z21 = 0.f, z22 = 1.f;
    int jtot = 0;
    int l1 = 1;

    while (true) {
        if (l1 > n) break;
        if (l1 > 1) ESET(l1 - 2, 0.f);
        int m = n;
        {   // for (mi = l1; mi <= n-1; ++mi) with first-hit break
            bool found = false;
            #pragma unroll
            for (int mi = 1; mi <= 2; ++mi) {
                if (!found && mi >= l1) {
                    float tst = fabsf(EGET(mi - 1));
                    if (tst == 0.f) { m = mi; found = true; }
                    else if (tst <= (sqrtf(fabsf(DGET(mi - 1))) * sqrtf(fabsf(DGET(mi)))) * eps) {
                        ESET(mi - 1, 0.f); m = mi; found = true;
                    }
                }
            }
        }
        int l = l1, lsv = l, lend = m, lendsv = lend;
        l1 = m + 1;
        if (lend == l) continue;

        float anorm = 0.f;
        #pragma unroll
        for (int i = 1; i <= 3; ++i)
            if (i >= l && i <= lend) anorm = fmaxf(anorm, fabsf(DGET(i - 1)));
        #pragma unroll
        for (int i = 1; i <= 2; ++i)
            if (i >= l && i <= lend - 1) anorm = fmaxf(anorm, fabsf(EGET(i - 1)));
        int iscale = 0; float sclto = 1.f;
        if (anorm == 0.f) continue;
        if (anorm > ssfmax) { iscale = 1; sclto = ssfmax; }
        else if (anorm < ssfmin) { iscale = 2; sclto = ssfmin; }
        if (iscale) {
            float mul = sclto / anorm;
            #pragma unroll
            for (int i = 1; i <= 3; ++i)
                if (i >= l && i <= lend) DSET(i - 1, DGET(i - 1) * mul);
            #pragma unroll
            for (int i = 1; i <= 2; ++i)
                if (i >= l && i <= lend - 1) ESET(i - 1, EGET(i - 1) * mul);
        }
        if (fabsf(DGET(lend - 1)) < fabsf(DGET(l - 1))) { lend = lsv; l = lendsv; }

        if (lend > l) {
            // QL
            while (true) {
                int mq = lend;
                if (l != lend) {
                    bool found = false;
                    #pragma unroll
                    for (int i = 1; i <= 2; ++i) {
                        if (!found && i >= l && i <= lend - 1) {
                            float ei = EGET(i - 1);
                            float tst = ei * ei;
                            if (tst <= (eps2 * fabsf(DGET(i - 1))) * fabsf(DGET(i)) + safmin) { mq = i; found = true; }
                        }
                    }
                }
                if (mq < lend) ESET(mq - 1, 0.f);
                float p = DGET(l - 1);
                if (mq == l) { DSET(l - 1, p); l = l + 1; if (l <= lend) continue; break; }
                if (mq == l + 1) {
                    float rt1, rt2, c, s;
                    f_slaev2(DGET(l - 1), EGET(l - 1), DGET(l), &rt1, &rt2, &c, &s);
                    ZROT3(l, l - 1, c, s);
                    DSET(l - 1, rt1); DSET(l, rt2); ESET(l - 1, 0.f);
                    l += 2; if (l <= lend) continue; break;
                }
                if (jtot == nmaxit) break;
                jtot++;
                float g = (DGET(l) - p) / (2.f * EGET(l - 1));
                float r = f_slapy2(g, 1.f);
                g = DGET(mq - 1) - p + EGET(l - 1) / (g + copysignf(r, g));
                float s = 1.f, c = 1.f; p = 0.f;
                float cw0 = 0.f, cw1 = 0.f, sw0 = 0.f, sw1 = 0.f;
                // for (i = mq-1; i >= l; --i)
                #pragma unroll
                for (int i = 2; i >= 1; --i) {
                    if (i <= mq - 1 && i >= l) {
                        float f = s * EGET(i - 1);
                        float b = c * EGET(i - 1);
                        f_slartg(g, f, &c, &s, &r);
                        if (i != mq - 1) ESET(i, r);
                        g = DGET(i) - p;
                        r = (DGET(i - 1) - g) * s + 2.f * c * b;
                        p = s * r;
                        DSET(i, g + p);
                        g = c * r - b;
                        set2(cw0, cw1, i - l, c);
                        set2(sw0, sw1, i - l, -s);
                    }
                }
                // for (j = mq-l; j >= 1; --j)
                #pragma unroll
                for (int j = 2; j >= 1; --j) {
                    if (j <= mq - l) {
                        float cj = get2(cw0, cw1, j - 1), sj = get2(sw0, sw1, j - 1);
                        int c0 = l - 1 + (j - 1);
                        ZROT3(c0 + 1, c0, cj, sj);
                    }
                }
                DSET(l - 1, DGET(l - 1) - p);
                ESET(l - 1, g);
            }
        } else {
            // QR
            while (true) {
                int mq = lend;
                if (l != lend) {
                    bool found = false;
                    // for (i = l; i >= lend+1; --i)
                    #pragma unroll
                    for (int i = 3; i >= 2; --i) {
                        if (!found && i <= l && i >= lend + 1) {
                            float ei = EGET(i - 2);
                            float tst = ei * ei;
                            if (tst <= (eps2 * fabsf(DGET(i - 1))) * fabsf(DGET(i - 2)) + safmin) { mq = i; found = true; }
                        }
                    }
                }
                if (mq > lend) ESET(mq - 2, 0.f);
                float p = DGET(l - 1);
                if (mq == l) { DSET(l - 1, p); l = l - 1; if (l >= lend) continue; break; }
                if (mq == l - 1) {
                    float rt1, rt2, c, s;
                    f_slaev2(DGET(l - 2), EGET(l - 2), DGET(l - 1), &rt1, &rt2, &c, &s);
                    ZROT3(l - 1, l - 2, c, s);
                    DSET(l - 2, rt1); DSET(l - 1, rt2); ESET(l - 2, 0.f);
                    l -= 2; if (l >= lend) continue; break;
                }
                if (jtot == nmaxit) break;
                jtot++;
                float g = (DGET(l - 2) - p) / (2.f * EGET(l - 2));
                float r = f_slapy2(g, 1.f);
                g = DGET(mq - 1) - p + EGET(l - 2) / (g + copysignf(r, g));
                float s = 1.f, c = 1.f; p = 0.f;
                float cw0 = 0.f, cw1 = 0.f, sw0 = 0.f, sw1 = 0.f;
                // for (i = mq; i <= l-1; ++i)
                #pragma unroll
                for (int i = 1; i <= 2; ++i) {
                    if (i >= mq && i <= l - 1) {
                        float f = s * EGET(i - 1);
                        float b = c * EGET(i - 1);
                        f_slartg(g, f, &c, &s, &r);
                        if (i != mq) ESET(i - 2, r);
                        g = DGET(i - 1) - p;
                        r = (DGET(i) - g) * s + 2.f * c * b;
                        p = s * r;
                        DSET(i - 1, g + p);
                        g = c * r - b;
                        set2(cw0, cw1, i - mq, c);
                        set2(sw0, sw1, i - mq, s);
                    }
                }
                // for (j = 1; j <= l-mq; ++j)
                #pragma unroll
                for (int j = 1; j <= 2; ++j) {
                    if (j <= l - mq) {
                        float cj = get2(cw0, cw1, j - 1), sj = get2(sw0, sw1, j - 1);
                        int c0 = mq - 1 + (j - 1);
                        ZROT3(c0 + 1, c0, cj, sj);
                    }
                }
                DSET(l - 1, DGET(l - 1) - p);
                ESET(l - 2, g);
            }
        }
        if (iscale) {
            float mul = anorm / sclto;
            #pragma unroll
            for (int i = 1; i <= 3; ++i)
                if (i >= lsv && i <= lendsv) DSET(i - 1, DGET(i - 1) * mul);
            #pragma unroll
            for (int i = 1; i <= 2; ++i)
                if (i >= lsv && i <= lendsv - 1) ESET(i - 1, EGET(i - 1) * mul);
        }
        if (jtot >= nmaxit) break;
    }

    // sort ascending (column swaps — no sign change)
    #pragma unroll
    for (int ii = 2; ii <= 3; ++ii) {
        int i = ii - 1, k = i;
        float p = DGET(i - 1);
        #pragma unroll
        for (int j = ii; j <= 3; ++j)
            if (DGET(j - 1) < p) { k = j; p = DGET(j - 1); }
        if (k != i) {
            DSET(k - 1, DGET(i - 1)); DSET(i - 1, p);
            { float t0 = ZGET(0, i - 1); ZSET(0, i - 1, ZGET(0, k - 1)); ZSET(0, k - 1, t0); }
            { float t1 = ZGET(1, i - 1); ZSET(1, i - 1, ZGET(1, k - 1)); ZSET(1, k - 1, t1); }
            { float t2 = ZGET(2, i - 1); ZSET(2, i - 1, ZGET(2, k - 1)); ZSET(2, k - 1, t2); }
        }
    }
    // sormtr('L','L','N')
    float r0 = z00, r1 = z10, r2 = z20;
    if (tau != 0.f) {
        float sum = r1 + v2 * r2;
        r1 -= tau * sum;
        r2 -= tau * (v2 * sum);
    }
    *ox = r0; *oy = r1; *oz = r2;
}

// ---------------- common ----------------

__device__ __forceinline__ float dot_rn(float ax, float ay, float az,
                                        float bx, float by, float bz) {
    return __fadd_rn(__fadd_rn(__fmul_rn(ax, bx), __fmul_rn(ay, by)), __fmul_rn(az, bz));
}

// Branchless sorted-chain inserts: keys ascending; drops the largest.
__device__ __forceinline__ void chain10(unsigned k[KW], unsigned x) {
    unsigned t = x;
    #pragma unroll
    for (int s = 0; s < KW; ++s) {
        unsigned lo = k[s] < t ? k[s] : t;
        unsigned hi = k[s] < t ? t : k[s];
        k[s] = lo; t = hi;
    }
}
__device__ __forceinline__ void chain16(unsigned k[KN], unsigned x) {
    unsigned t = x;
    #pragma unroll
    for (int s = 0; s < KN; ++s) {
        unsigned lo = k[s] < t ? k[s] : t;
        unsigned hi = k[s] < t ? t : k[s];
        k[s] = lo; t = hi;
    }
}

// ---------------- Kernel A: scan only ----------------
// 512 blocks x 512 threads (8 waves), 2 blocks/CU (64KB LDS). Wave w scans
// interleaved slice j=8t+w keeping branchless sorted top-10 per lane-query +
// chamfer partial min, then stores keys+min straight to global (coalesced per
// (s,wave): 64 consecutive u32) and exits. No tail, no second barrier.
__global__ __launch_bounds__(512, 4) void scan_kernel(
    const float* __restrict__ pred, const float* __restrict__ gt,
    unsigned* __restrict__ kbuf_g, float* __restrict__ mbuf_g)
{
    __shared__ float4 sHome[NP];            // (x,y,z,|p|^2)  32 KB
    __shared__ float4 sOther[NP];           // (x,y,z,0)      32 KB

    int bi = blockIdx.x;
    bool predHome = bi < NB * 32;
    int lb = predHome ? bi : bi - NB * 32;
    int b = lb >> 5;
    int tile = lb & 31;
    int tid  = threadIdx.x;
    int wave = tid >> 6;
    int lane = tid & 63;

    const float* home  = (predHome ? pred : gt) + (size_t)b * NP * 3;
    const float* other = (predHome ? gt : pred) + (size_t)b * NP * 3;

    for (int t = tid; t < NP; t += 512) {
        float hx = home[3 * t], hy = home[3 * t + 1], hz = home[3 * t + 2];
        sHome[t] = make_float4(hx, hy, hz, dot_rn(hx, hy, hz, hx, hy, hz));
        float ox = other[3 * t], oy = other[3 * t + 1], oz = other[3 * t + 2];
        sOther[t] = make_float4(ox, oy, oz, 0.f);
    }
    __syncthreads();

    int im = tile * 64 + lane;              // original index of this lane's query
    float4 qv = sHome[im];
    float qx = qv.x, qy = qv.y, qz = qv.z, qq = qv.w;

    unsigned keys[KW];
    #pragma unroll
    for (int s = 0; s < KW; ++s) keys[s] = 0x7F800000u | (unsigned)s;  // sorted inf seeds

    float minv = 1e30f;

    for (int t = 0; t < NP / 8; ++t) {
        int jj = (t << 3) | wave;
        float4 h = sHome[jj];                                  // broadcast b128
        float dotj = dot_rn(qx, qy, qz, h.x, h.y, h.z);
        float d2 = __fsub_rn(__fadd_rn(qq, h.w), __fmul_rn(2.f, dotj));
        chain10(keys, (__float_as_uint(d2) & 0xFFFFF800u) | (unsigned)jj);
        float4 o = sOther[jj];                                 // broadcast b128
        float ex = qx - o.x, ey = qy - o.y, ez = qz - o.z;
        minv = fminf(minv, fmaf(ex, ex, fmaf(ey, ey, ez * ez)));
    }

    // store sorted top-10 + chamfer min straight to global (coalesced per (s,wave))
    size_t gq = (size_t)(predHome ? 0 : NB * NP) + (size_t)b * NP + im;
    #pragma unroll
    for (int s = 0; s < KW; ++s)
        kbuf_g[(size_t)(s * 8 + wave) * NQ + gq] = keys[s];
    mbuf_g[(size_t)wave * NQ + gq] = minv;
}

// ---------------- Kernel B: tail spread across ALL CUs, dot fused ----------------
// 256 blocks x 128 threads (2 waves) = 512 waves over 256 CUs (1 block/CU).
// Wave 0: pred query i = bid*64+lane. Wave 1: gt query i (same index). Each
// lane: merge 8x10 keys (register double-buffered prefetch; guarded chain16
// skip is a provable no-op when kk >= k16[15]), violation fallback recomputes
// from global (bit-identical fp32), repulsion (pred only), covariance gather
// from global, in-register ssyevd. Wave 1 stages nG in LDS; wave 0 dots vs
// register nP (fp32 triple product like old dot_kernel terms, double combine).
// Per-block combined partial (cd + rep - 0.01*dot contribution) -> cdpart[bid].
__global__ __launch_bounds__(128) void tail_kernel(
    const float* __restrict__ pred, const float* __restrict__ gt,
    const unsigned* __restrict__ kbuf_g, const float* __restrict__ mbuf_g,
    double* __restrict__ cdpart)
{
    __shared__ float sNG[64 * 3];
    __shared__ double wsum[2];
    int tid = threadIdx.x;
    int wave = tid >> 6, lane = tid & 63;
    int i = blockIdx.x * 64 + lane;                       // 0..16383 (per-cloud index)
    bool predHome = (wave == 0);
    size_t gq = (size_t)(predHome ? 0 : NB * NP) + (size_t)i;

    int b  = i >> 11;                                     // /NP
    int im = i & (NP - 1);
    const float* home = (predHome ? pred : gt) + (size_t)b * NP * 3;

    float qx = home[3 * im], qy = home[3 * im + 1], qz = home[3 * im + 2];
    float qq = dot_rn(qx, qy, qz, qx, qy, qz);            // == sHome[im].w bitwise

    // --- merge 8x10 -> sorted top-16, register-double-buffered ---
    unsigned k16[KN];
    unsigned tenth[8];                                    // constant-indexed after unroll
    #pragma unroll
    for (int s = 0; s < KW; ++s) k16[s] = kbuf_g[(size_t)(s * 8 + 0) * NQ + gq];
    tenth[0] = k16[KW - 1];
    #pragma unroll
    for (int s = KW; s < KN; ++s) k16[s] = 0x7F800000u | (unsigned)s;  // seeds (> any real)

    unsigned kc[KW], kn[KW];
    #pragma unroll
    for (int s = 0; s < KW; ++s) kc[s] = kbuf_g[(size_t)(s * 8 + 1) * NQ + gq];
    #pragma unroll
    for (int w = 1; w < 8; ++w) {
        if (w < 7) {
            #pragma unroll
            for (int s = 0; s < KW; ++s) kn[s] = kbuf_g[(size_t)(s * 8 + (w + 1)) * NQ + gq];
        }
        tenth[w] = kc[KW - 1];
        #pragma unroll
        for (int s = 0; s < KW; ++s) {
            unsigned kk = kc[s];
            if (__any(kk < k16[KN - 1])) chain16(k16, kk);  // skip = provable no-op
        }
        if (w < 7) {
            #pragma unroll
            for (int s = 0; s < KW; ++s) kc[s] = kn[s];
        }
    }
    float minv = fminf(fminf(fminf(mbuf_g[0 * NQ + gq], mbuf_g[1 * NQ + gq]),
                             fminf(mbuf_g[2 * NQ + gq], mbuf_g[3 * NQ + gq])),
                       fminf(fminf(mbuf_g[4 * NQ + gq], mbuf_g[5 * NQ + gq]),
                             fminf(mbuf_g[6 * NQ + gq], mbuf_g[7 * NQ + gq])));

    // --- violation detect from register-held tenth keys ---
    unsigned flags = 0;
    #pragma unroll
    for (int w = 0; w < 8; ++w)
        flags |= (tenth[w] < k16[KN - 1]) ? (1u << w) : 0u;

    if (__any(flags != 0)) {                 // ~0.07 expected events per LAUNCH
        #pragma unroll
        for (int s = 0; s < KN; ++s)
            k16[s] = flags ? (0x7F800000u | (unsigned)s) : k16[s];   // reinit flagged lanes
        for (int w = 0; w < 8; ++w) {
            #pragma unroll
            for (int s = 0; s < KW; ++s) {
                unsigned kk = kbuf_g[(size_t)(s * 8 + w) * NQ + gq];
                bool use = (flags != 0) && !((flags >> w) & 1);
                chain16(k16, use ? kk : 0xFFFFFFFFu);          // inf = no-op
            }
        }
        for (int w = 0; w < 8; ++w) {
            if (__any((flags >> w) & 1)) {
                bool actw = ((flags >> w) & 1) != 0;
                for (int t = 0; t < NP / 8; ++t) {
                    int jj = (t << 3) | w;
                    float hx = home[3 * jj], hy = home[3 * jj + 1], hz = home[3 * jj + 2];
                    float hw = dot_rn(hx, hy, hz, hx, hy, hz);
                    float dotj = dot_rn(qx, qy, qz, hx, hy, hz);
                    float d2 = __fsub_rn(__fadd_rn(qq, hw), __fmul_rn(2.f, dotj));
                    unsigned key = (__float_as_uint(d2) & 0xFFFFF800u) | (unsigned)jj;
                    chain16(k16, actw ? key : 0xFFFFFFFFu);
                }
            }
        }
    }

    // --- repulsion: k16 sorted ascending, slot 0 = self (d2=0) -> slots 1..4 ---
    float rep = 0.0f;
    if (predHome) {
        #pragma unroll
        for (int r = 1; r <= 4; ++r) {
            float d2 = __uint_as_float(k16[r] & 0xFFFFF800u);
            float dd = sqrtf(fmaxf(d2, 1e-12f));
            rep += fmaxf(0.02f - dd, 0.0f);
        }
    }

    // --- covariance over the 16-NN: gather from global (values bit-identical
    //     to kernel A's staging; same summation order; loads independent) ---
    float sx = 0.f, sy = 0.f, sz = 0.f;
    #pragma unroll
    for (int s = 0; s < KN; ++s) {
        const float* hp = home + 3 * (size_t)(k16[s] & 0x7FFu);
        sx += hp[0]; sy += hp[1]; sz += hp[2];
    }
    float mx = sx * (1.0f / KN), my = sy * (1.0f / KN), mz = sz * (1.0f / KN);
    float cxx = 0.f, cxy = 0.f, cxz = 0.f, cyy = 0.f, cyz = 0.f, czz = 0.f;
    #pragma unroll
    for (int s = 0; s < KN; ++s) {
        const float* hp = home + 3 * (size_t)(k16[s] & 0x7FFu);
        float ax = hp[0] - mx;
        float ay = hp[1] - my;
        float az = hp[2] - mz;
        cxx += ax * ax; cxy += ax * ay; cxz += ax * az;
        cyy += ay * ay; cyz += ay * az; czz += az * az;
    }
    cxx *= (1.f / KN); cxy *= (1.f / KN); cxz *= (1.f / KN);
    cyy *= (1.f / KN); cyz *= (1.f / KN); czz *= (1.f / KN);

    // --- normal via faithful ssyevd emulation (register-resident) ---
    float nx, ny, nz;
    ssyevd3_evec0(cxx, cxy, cxz, cyy, cyz, czz, &nx, &ny, &nz);

    // --- wave 1 stages nG; wave 0 dots vs register nP ---
    if (!predHome) {
        sNG[lane * 3 + 0] = nx;
        sNG[lane * 3 + 1] = ny;
        sNG[lane * 3 + 2] = nz;
    }
    __syncthreads();

    double part;
    if (predHome) {
        float gx = sNG[lane * 3 + 0];
        float gy = sNG[lane * 3 + 1];
        float gz = sNG[lane * 3 + 2];
        float dotv = nx * gx + ny * gy + nz * gz;     // fp32, like old dot_kernel terms
        part = (double)minv * (1.0 / (NB * NP))
             + (double)rep  * (0.1 / (NB * NP * 4))
             - (double)dotv * (0.01 / (NB * NP));
    } else {
        part = (double)minv * (1.0 / (NB * NP));
    }

    #pragma unroll
    for (int off = 32; off > 0; off >>= 1) part += __shfl_down(part, off);
    if (lane == 0) wsum[wave] = part;
    __syncthreads();
    if (tid == 0) cdpart[blockIdx.x] = wsum[0] + wsum[1];
}

// ---------------------------------------------------------------------------
// Micro-finalize: 1 wave. Reduce 256 cdpart doubles (4 per lane), write out.
__global__ __launch_bounds__(64) void fin_kernel(
    const double* __restrict__ cdpart, float* __restrict__ out)
{
    int tid = threadIdx.x;
    double c = cdpart[tid] + cdpart[tid + 64] + cdpart[tid + 128] + cdpart[tid + 192];
    #pragma unroll
    for (int off = 32; off > 0; off >>= 1) c += __shfl_down(c, off);
    if (tid == 0)
        out[0] = (float)(c + 0.01);
}

// ---------------------------------------------------------------------------
extern "C" void kernel_launch(void* const* d_in, const int* in_sizes, int n_in,
                              void* d_out, int out_size, void* d_ws, size_t ws_size,
                              hipStream_t stream)
{
    const float* pred = (const float*)d_in[0];
    const float* gt   = (const float*)d_in[1];

    // ws layout: cdpart (256 f64 = 2KB, padded to 4KB) | mbuf_g (1MB) |
    //            kbuf_g (10.5MB). No memset: every slot written before read.
    char* base = (char*)d_ws;
    double*   cdpart = (double*)base;
    float*    mbuf_g = (float*)(base + 4096);
    unsigned* kbuf_g = (unsigned*)(base + 4096 + (size_t)NQ * 8 * 4);

    scan_kernel<<<dim3(NB * 32 * 2), dim3(512), 0, stream>>>(pred, gt, kbuf_g, mbuf_g);
    tail_kernel<<<dim3(256), dim3(128), 0, stream>>>(pred, gt, kbuf_g, mbuf_g, cdpart);
    fin_kernel<<<dim3(1), dim3(64), 0, stream>>>(cdpart, (float*)d_out);
}

// Round 10
// 179.489 us; speedup vs baseline: 1.1646x; 1.0403x over previous
//
#include <hip/hip_runtime.h>

// CombinedLoss: chamfer(pred,gt) + 0.1*repulsion(pred,k=4) + 0.01*(1 - mean(n_pred . n_gt))
// B=8, N=2048, fp32 in, fp32 scalar out.
// Normals match np.linalg.eigh (LAPACK ssyevd) signs point-by-point via faithful
// fp32 ssytd2+ssteqr+sormtr emulation (R3-R7: absmax 0.0).
// R8: branchless sorted-chain top-10 per wave-slice + exact top-16 merge.
// R9: eigensolver state in named registers. R13: masked tail regressed.
// R15/R16/R17: tail wall-time INVARIANT to CU count (90/73/75us at 64/32/256
// CUs) -> tail == ONE wave's serial chain latency. R16 math: issue work only
// ~25K cyc; ~150K cyc is exposed memory latency = loads serialized. Root
// cause: VGPR_Count=44 - merge needs 44 live regs, ZERO left for loads in
// flight; default occupancy target strangled the register budget.
// R18: tail gets registers. __launch_bounds__(128,1) (VGPR cap ~512, occupancy
// irrelevant at 2 waves/CU). All 80 merge keys + 8 mins hoisted into kall[8][10]
// regs upfront (88 independent loads -> ONE latency); inserts register-only,
// byte-identical sequence; violation repair reads kall (same values as the
// reload it replaces). Covariance: 48 floats loaded once into regs (16
// independent loads, one latency); both passes read regs (second pass re-read
// unchanged memory -> bit-identical). Scan/fin unchanged. 3 launches.

#define NB 8
#define NP 2048
#define KW 10     // per-slice kept keys
#define KN 16
#define NQ (2 * NB * NP)   // 32768 queries (both clouds)

// ---------------- LAPACK helpers (fp32, faithful — DO NOT TOUCH) ----------------

__device__ __forceinline__ float f_slapy2(float x, float y) {
    float xa = fabsf(x), ya = fabsf(y);
    float w = fmaxf(xa, ya), zm = fminf(xa, ya);
    if (zm == 0.f) return w;
    float q = zm / w;
    return w * sqrtf(1.f + q * q);
}

// LAPACK >=3.10 slartg convention: c >= 0 always.
__device__ __forceinline__ void f_slartg(float f, float g, float* cs, float* sn, float* r) {
    if (g == 0.f) { *cs = 1.f; *sn = 0.f; *r = f; }
    else if (f == 0.f) { *cs = 0.f; *sn = copysignf(1.f, g); *r = fabsf(g); }
    else {
        float d = sqrtf(__fadd_rn(__fmul_rn(f, f), __fmul_rn(g, g)));
        *cs = fabsf(f) / d;
        *r  = copysignf(d, f);
        *sn = g / *r;
    }
}

__device__ void f_slaev2(float a, float b, float c,
                         float* rt1, float* rt2, float* cs1, float* sn1) {
    float sm = a + c;
    float df = a - c;
    float adf = fabsf(df);
    float tb = b + b;
    float ab = fabsf(tb);
    float acmx, acmn;
    if (fabsf(a) > fabsf(c)) { acmx = a; acmn = c; } else { acmx = c; acmn = a; }
    float rt;
    if (adf > ab)      { float q = ab / adf; rt = adf * sqrtf(1.f + q * q); }
    else if (adf < ab) { float q = adf / ab; rt = ab * sqrtf(1.f + q * q); }
    else               rt = ab * sqrtf(2.f);
    int sgn1;
    if (sm < 0.f) {
        *rt1 = 0.5f * (sm - rt); sgn1 = -1;
        *rt2 = (acmx / *rt1) * acmn - (b / *rt1) * b;
    } else if (sm > 0.f) {
        *rt1 = 0.5f * (sm + rt); sgn1 = 1;
        *rt2 = (acmx / *rt1) * acmn - (b / *rt1) * b;
    } else {
        *rt1 = 0.5f * rt; *rt2 = -0.5f * rt; sgn1 = 1;
    }
    float cs; int sgn2;
    if (df >= 0.f) { cs = df + rt; sgn2 = 1; }
    else           { cs = df - rt; sgn2 = -1; }
    float acs = fabsf(cs);
    if (acs > ab) {
        float ct = -tb / cs;
        *sn1 = 1.f / sqrtf(1.f + ct * ct);
        *cs1 = ct * *sn1;
    } else {
        if (ab == 0.f) { *cs1 = 1.f; *sn1 = 0.f; }
        else {
            float tn = -cs / tb;
            *cs1 = 1.f / sqrtf(1.f + tn * tn);
            *sn1 = tn * *cs1;
        }
    }
    if (sgn1 == sgn2) { float tn = *cs1; *cs1 = -*sn1; *sn1 = tn; }
}

// --------- register-resident dynamic indexing (R9: replaces scratch arrays) ---------
// Selection only — bit-exact with array loads/stores; compiles to v_cndmask, no memory.

__device__ __forceinline__ float get3(float a, float b, float c, int i) {
    return i == 0 ? a : (i == 1 ? b : c);
}
__device__ __forceinline__ void set3(float& a, float& b, float& c, int i, float v) {
    a = (i == 0) ? v : a;
    b = (i == 1) ? v : b;
    c = (i == 2) ? v : c;
}
__device__ __forceinline__ float get2(float a, float b, int i) { return i == 0 ? a : b; }
__device__ __forceinline__ void set2(float& a, float& b, int i, float v) {
    a = (i == 0) ? v : a;
    b = (i == 1) ? v : b;
}

#define DGET(i)    get3(dd0, dd1, dd2, (i))
#define DSET(i, v) set3(dd0, dd1, dd2, (i), (v))
#define EGET(i)    get2(ee0, ee1, (i))
#define ESET(i, v) set2(ee0, ee1, (i), (v))
#define ZGET(r, c)    get3(z##r##0, z##r##1, z##r##2, (c))
#define ZSET(r, c, v) set3(z##r##0, z##r##1, z##r##2, (c), (v))
// Two-column Givens update: cols (ca,cb) <- (cc*ca - ss*cb, ss*ca + cc*cb), all 3 rows.
#define ZROT(r, ca, cb, cc, ss) { float zt_ = ZGET(r, (ca)); float zb_ = ZGET(r, (cb)); \
    ZSET(r, (ca), (cc) * zt_ - (ss) * zb_); ZSET(r, (cb), (ss) * zt_ + (cc) * zb_); }
#define ZROT3(ca, cb, cc, ss) { ZROT(0, (ca), (cb), (cc), (ss)) ZROT(1, (ca), (cb), (cc), (ss)) ZROT(2, (ca), (cb), (cc), (ss)) }

// fp32 ssyevd for a 3x3 symmetric matrix (lower triangle given), returns
// eigenvector of the SMALLEST eigenvalue, with LAPACK's sign convention.
__device__ void ssyevd3_evec0(float a00, float a10, float a20,
                              float a11, float a21, float a22,
                              float* ox, float* oy, float* oz) {
    // ---- ssytd2('L') ----
    float dd0, dd1, dd2, ee0, ee1;
    float tau = 0.f, v2 = 0.f;
    float xnorm = fabsf(a20);
    if (xnorm == 0.f) {
        tau = 0.f;
        dd0 = a00; dd1 = a11; dd2 = a22; ee0 = a10; ee1 = a21;
    } else {
        float beta = -copysignf(f_slapy2(a10, xnorm), a10);
        tau = (beta - a10) / beta;
        float inv = 1.f / (a10 - beta);
        v2 = a20 * inv;
        float x1 = tau * (a11 + a21 * v2);
        float x2 = tau * (a21 + a22 * v2);
        float alpha = -0.5f * tau * (x1 + x2 * v2);
        float w1 = x1 + alpha;
        float w2 = x2 + alpha * v2;
        float b11 = a11 - 2.f * w1;
        float b21 = a21 - v2 * w1 - w2;
        float b22 = a22 - 2.f * (v2 * w2);
        dd0 = a00; dd1 = b11; dd2 = b22; ee0 = beta; ee1 = b21;
    }
    // ---- ssteqr('I', n=3) ----
    const float eps    = 5.9604645e-08f;
    const float eps2   = eps * eps;
    const float safmin = 1.1754944e-38f;
    const float ssfmax = sqrtf(1.f / safmin) / 3.f;
    const float ssfmin = sqrtf(safmin) / eps2;
    const int n = 3, nmaxit = 90;
    float z00 = 1.f, z01 = 0.f, z02 = 0.f;
    float z10 = 0.f, z11 = 1.f, z12 = 0.f;
    float z20 = 0.f, z21 = 0.f, z22 = 1.f;
    int jtot = 0;
    int l1 = 1;

    while (true) {
        if (l1 > n) break;
        if (l1 > 1) ESET(l1 - 2, 0.f);
        int m = n;
        {   // for (mi = l1; mi <= n-1; ++mi) with first-hit break
            bool found = false;
            #pragma unroll
            for (int mi = 1; mi <= 2; ++mi) {
                if (!found && mi >= l1) {
                    float tst = fabsf(EGET(mi - 1));
                    if (tst == 0.f) { m = mi; found = true; }
                    else if (tst <= (sqrtf(fabsf(DGET(mi - 1))) * sqrtf(fabsf(DGET(mi)))) * eps) {
                        ESET(mi - 1, 0.f); m = mi; found = true;
                    }
                }
            }
        }
        int l = l1, lsv = l, lend = m, lendsv = lend;
        l1 = m + 1;
        if (lend == l) continue;

        float anorm = 0.f;
        #pragma unroll
        for (int i = 1; i <= 3; ++i)
            if (i >= l && i <= lend) anorm = fmaxf(anorm, fabsf(DGET(i - 1)));
        #pragma unroll
        for (int i = 1; i <= 2; ++i)
            if (i >= l && i <= lend - 1) anorm = fmaxf(anorm, fabsf(EGET(i - 1)));
        int iscale = 0; float sclto = 1.f;
        if (anorm == 0.f) continue;
        if (anorm > ssfmax) { iscale = 1; sclto = ssfmax; }
        else if (anorm < ssfmin) { iscale = 2; sclto = ssfmin; }
        if (iscale) {
            float mul = sclto / anorm;
            #pragma unroll
            for (int i = 1; i <= 3; ++i)
                if (i >= l && i <= lend) DSET(i - 1, DGET(i - 1) * mul);
            #pragma unroll
            for (int i = 1; i <= 2; ++i)
                if (i >= l && i <= lend - 1) ESET(i - 1, EGET(i - 1) * mul);
        }
        if (fabsf(DGET(lend - 1)) < fabsf(DGET(l - 1))) { lend = lsv; l = lendsv; }

        if (lend > l) {
            // QL
            while (true) {
                int mq = lend;
                if (l != lend) {
                    bool found = false;
                    #pragma unroll
                    for (int i = 1; i <= 2; ++i) {
                        if (!found && i >= l && i <= lend - 1) {
                            float ei = EGET(i - 1);
                            float tst = ei * ei;
                            if (tst <= (eps2 * fabsf(DGET(i - 1))) * fabsf(DGET(i)) + safmin) { mq = i; found = true; }
                        }
                    }
                }
                if (mq < lend) ESET(mq - 1, 0.f);
                float p = DGET(l - 1);
                if (mq == l) { DSET(l - 1, p); l = l + 1; if (l <= lend) continue; break; }
                if (mq == l + 1) {
                    float rt1, rt2, c, s;
                    f_slaev2(DGET(l - 1), EGET(l - 1), DGET(l), &rt1, &rt2, &c, &s);
                    ZROT3(l, l - 1, c, s);
                    DSET(l - 1, rt1); DSET(l, rt2); ESET(l - 1, 0.f);
                    l += 2; if (l <= lend) continue; break;
                }
                if (jtot == nmaxit) break;
                jtot++;
                float g = (DGET(l) - p) / (2.f * EGET(l - 1));
                float r = f_slapy2(g, 1.f);
                g = DGET(mq - 1) - p + EGET(l - 1) / (g + copysignf(r, g));
                float s = 1.f, c = 1.f; p = 0.f;
                float cw0 = 0.f, cw1 = 0.f, sw0 = 0.f, sw1 = 0.f;
                // for (i = mq-1; i >= l; --i)
                #pragma unroll
                for (int i = 2; i >= 1; --i) {
                    if (i <= mq - 1 && i >= l) {
                        float f = s * EGET(i - 1);
                        float b = c * EGET(i - 1);
                        f_slartg(g, f, &c, &s, &r);
                        if (i != mq - 1) ESET(i, r);
                        g = DGET(i) - p;
                        r = (DGET(i - 1) - g) * s + 2.f * c * b;
                        p = s * r;
                        DSET(i, g + p);
                        g = c * r - b;
                        set2(cw0, cw1, i - l, c);
                        set2(sw0, sw1, i - l, -s);
                    }
                }
                // for (j = mq-l; j >= 1; --j)
                #pragma unroll
                for (int j = 2; j >= 1; --j) {
                    if (j <= mq - l) {
                        float cj = get2(cw0, cw1, j - 1), sj = get2(sw0, sw1, j - 1);
                        int c0 = l - 1 + (j - 1);
                        ZROT3(c0 + 1, c0, cj, sj);
                    }
                }
                DSET(l - 1, DGET(l - 1) - p);
                ESET(l - 1, g);
            }
        } else {
            // QR
            while (true) {
                int mq = lend;
                if (l != lend) {
                    bool found = false;
                    // for (i = l; i >= lend+1; --i)
                    #pragma unroll
                    for (int i = 3; i >= 2; --i) {
                        if (!found && i <= l && i >= lend + 1) {
                            float ei = EGET(i - 2);
                            float tst = ei * ei;
                            if (tst <= (eps2 * fabsf(DGET(i - 1))) * fabsf(DGET(i - 2)) + safmin) { mq = i; found = true; }
                        }
                    }
                }
                if (mq > lend) ESET(mq - 2, 0.f);
                float p = DGET(l - 1);
                if (mq == l) { DSET(l - 1, p); l = l - 1; if (l >= lend) continue; break; }
                if (mq == l - 1) {
                    float rt1, rt2, c, s;
                    f_slaev2(DGET(l - 2), EGET(l - 2), DGET(l - 1), &rt1, &rt2, &c, &s);
                    ZROT3(l - 1, l - 2, c, s);
                    DSET(l - 2, rt1); DSET(l - 1, rt2); ESET(l - 2, 0.f);
                    l -= 2; if (l >= lend) continue; break;
                }
                if (jtot == nmaxit) break;
                jtot++;
                float g = (DGET(l - 2) - p) / (2.f * EGET(l - 2));
                float r = f_slapy2(g, 1.f);
                g = DGET(mq - 1) - p + EGET(l - 2) / (g + copysignf(r, g));
                float s = 1.f, c = 1.f; p = 0.f;
                float cw0 = 0.f, cw1 = 0.f, sw0 = 0.f, sw1 = 0.f;
                // for (i = mq; i <= l-1; ++i)
                #pragma unroll
                for (int i = 1; i <= 2; ++i) {
                    if (i >= mq && i <= l - 1) {
                        float f = s * EGET(i - 1);
                        float b = c * EGET(i - 1);
                        f_slartg(g, f, &c, &s, &r);
                        if (i != mq) ESET(i - 2, r);
                        g = DGET(i - 1) - p;
                        r = (DGET(i) - g) * s + 2.f * c * b;
                        p = s * r;
                        DSET(i - 1, g + p);
                        g = c * r - b;
                        set2(cw0, cw1, i - mq, c);
                        set2(sw0, sw1, i - mq, s);
                    }
                }
                // for (j = 1; j <= l-mq; ++j)
                #pragma unroll
                for (int j = 1; j <= 2; ++j) {
                    if (j <= l - mq) {
                        float cj = get2(cw0, cw1, j - 1), sj = get2(sw0, sw1, j - 1);
                        int c0 = mq - 1 + (j - 1);
                        ZROT3(c0 + 1, c0, cj, sj);
                    }
                }
                DSET(l - 1, DGET(l - 1) - p);
                ESET(l - 2, g);
            }
        }
        if (iscale) {
            float mul = anorm / sclto;
            #pragma unroll
            for (int i = 1; i <= 3; ++i)
                if (i >= lsv && i <= lendsv) DSET(i - 1, DGET(i - 1) * mul);
            #pragma unroll
            for (int i = 1; i <= 2; ++i)
                if (i >= lsv && i <= lendsv - 1) ESET(i - 1, EGET(i - 1) * mul);
        }
        if (jtot >= nmaxit) break;
    }

    // sort ascending (column swaps — no sign change)
    #pragma unroll
    for (int ii = 2; ii <= 3; ++ii) {
        int i = ii - 1, k = i;
        float p = DGET(i - 1);
        #pragma unroll
        for (int j = ii; j <= 3; ++j)
            if (DGET(j - 1) < p) { k = j; p = DGET(j - 1); }
        if (k != i) {
            DSET(k - 1, DGET(i - 1)); DSET(i - 1, p);
            { float t0 = ZGET(0, i - 1); ZSET(0, i - 1, ZGET(0, k - 1)); ZSET(0, k - 1, t0); }
            { float t1 = ZGET(1, i - 1); ZSET(1, i - 1, ZGET(1, k - 1)); ZSET(1, k - 1, t1); }
            { float t2 = ZGET(2, i - 1); ZSET(2, i - 1, ZGET(2, k - 1)); ZSET(2, k - 1, t2); }
        }
    }
    // sormtr('L','L','N')
    float r0 = z00, r1 = z10, r2 = z20;
    if (tau != 0.f) {
        float sum = r1 + v2 * r2;
        r1 -= tau * sum;
        r2 -= tau * (v2 * sum);
    }
    *ox = r0; *oy = r1; *oz = r2;
}

// ---------------- common ----------------

__device__ __forceinline__ float dot_rn(float ax, float ay, float az,
                                        float bx, float by, float bz) {
    return __fadd_rn(__fadd_rn(__fmul_rn(ax, bx), __fmul_rn(ay, by)), __fmul_rn(az, bz));
}

// Branchless sorted-chain inserts: keys ascending; drops the largest.
__device__ __forceinline__ void chain10(unsigned k[KW], unsigned x) {
    unsigned t = x;
    #pragma unroll
    for (int s = 0; s < KW; ++s) {
        unsigned lo = k[s] < t ? k[s] : t;
        unsigned hi = k[s] < t ? t : k[s];
        k[s] = lo; t = hi;
    }
}
__device__ __forceinline__ void chain16(unsigned k[KN], unsigned x) {
    unsigned t = x;
    #pragma unroll
    for (int s = 0; s < KN; ++s) {
        unsigned lo = k[s] < t ? k[s] : t;
        unsigned hi = k[s] < t ? t : k[s];
        k[s] = lo; t = hi;
    }
}

// ---------------- Kernel A: scan only ----------------
// 512 blocks x 512 threads (8 waves), 2 blocks/CU (64KB LDS). Wave w scans
// interleaved slice j=8t+w keeping branchless sorted top-10 per lane-query +
// chamfer partial min, then stores keys+min straight to global (coalesced per
// (s,wave): 64 consecutive u32) and exits. No tail, no second barrier.
__global__ __launch_bounds__(512, 4) void scan_kernel(
    const float* __restrict__ pred, const float* __restrict__ gt,
    unsigned* __restrict__ kbuf_g, float* __restrict__ mbuf_g)
{
    __shared__ float4 sHome[NP];            // (x,y,z,|p|^2)  32 KB
    __shared__ float4 sOther[NP];           // (x,y,z,0)      32 KB

    int bi = blockIdx.x;
    bool predHome = bi < NB * 32;
    int lb = predHome ? bi : bi - NB * 32;
    int b = lb >> 5;
    int tile = lb & 31;
    int tid  = threadIdx.x;
    int wave = tid >> 6;
    int lane = tid & 63;

    const float* home  = (predHome ? pred : gt) + (size_t)b * NP * 3;
    const float* other = (predHome ? gt : pred) + (size_t)b * NP * 3;

    for (int t = tid; t < NP; t += 512) {
        float hx = home[3 * t], hy = home[3 * t + 1], hz = home[3 * t + 2];
        sHome[t] = make_float4(hx, hy, hz, dot_rn(hx, hy, hz, hx, hy, hz));
        float ox = other[3 * t], oy = other[3 * t + 1], oz = other[3 * t + 2];
        sOther[t] = make_float4(ox, oy, oz, 0.f);
    }
    __syncthreads();

    int im = tile * 64 + lane;              // original index of this lane's query
    float4 qv = sHome[im];
    float qx = qv.x, qy = qv.y, qz = qv.z, qq = qv.w;

    unsigned keys[KW];
    #pragma unroll
    for (int s = 0; s < KW; ++s) keys[s] = 0x7F800000u | (unsigned)s;  // sorted inf seeds

    float minv = 1e30f;

    for (int t = 0; t < NP / 8; ++t) {
        int jj = (t << 3) | wave;
        float4 h = sHome[jj];                                  // broadcast b128
        float dotj = dot_rn(qx, qy, qz, h.x, h.y, h.z);
        float d2 = __fsub_rn(__fadd_rn(qq, h.w), __fmul_rn(2.f, dotj));
        chain10(keys, (__float_as_uint(d2) & 0xFFFFF800u) | (unsigned)jj);
        float4 o = sOther[jj];                                 // broadcast b128
        float ex = qx - o.x, ey = qy - o.y, ez = qz - o.z;
        minv = fminf(minv, fmaf(ex, ex, fmaf(ey, ey, ez * ez)));
    }

    // store sorted top-10 + chamfer min straight to global (coalesced per (s,wave))
    size_t gq = (size_t)(predHome ? 0 : NB * NP) + (size_t)b * NP + im;
    #pragma unroll
    for (int s = 0; s < KW; ++s)
        kbuf_g[(size_t)(s * 8 + wave) * NQ + gq] = keys[s];
    mbuf_g[(size_t)wave * NQ + gq] = minv;
}

// ---------------- Kernel B: tail, all CUs, register-resident loads ----------------
// 256 blocks x 128 threads (2 waves), 1 block/CU. Wave 0 = pred query i, wave 1
// = gt query i. launch_bounds(128,1): VGPR budget up to ~512 so ALL loads stay
// in flight. kall[8][10] + mall[8] loaded upfront (88 independent loads -> one
// latency); merge insert sequence byte-identical (guarded chain16, same order);
// violation repair reads kall regs (same values as the old kbuf_g reload).
// Covariance: 48 floats loaded once into px/py/pz regs (one latency); both
// passes read regs (second pass re-read unchanged memory -> bit-identical).
// Wave 1 stages nG in LDS; wave 0 dots vs register nP. 1 partial per block.
__global__ __launch_bounds__(128, 1) void tail_kernel(
    const float* __restrict__ pred, const float* __restrict__ gt,
    const unsigned* __restrict__ kbuf_g, const float* __restrict__ mbuf_g,
    double* __restrict__ cdpart)
{
    __shared__ float sNG[64 * 3];
    __shared__ double wsum[2];
    int tid = threadIdx.x;
    int wave = tid >> 6, lane = tid & 63;
    int i = blockIdx.x * 64 + lane;                       // 0..16383 (per-cloud index)
    bool predHome = (wave == 0);
    size_t gq = (size_t)(predHome ? 0 : NB * NP) + (size_t)i;

    int b  = i >> 11;                                     // /NP
    int im = i & (NP - 1);
    const float* home = (predHome ? pred : gt) + (size_t)b * NP * 3;

    float qx = home[3 * im], qy = home[3 * im + 1], qz = home[3 * im + 2];
    float qq = dot_rn(qx, qy, qz, qx, qy, qz);            // == sHome[im].w bitwise

    // --- hoist ALL merge inputs into registers (88 independent loads) ---
    unsigned kall[8][KW];
    float mall[8];
    #pragma unroll
    for (int w = 0; w < 8; ++w) {
        #pragma unroll
        for (int s = 0; s < KW; ++s)
            kall[w][s] = kbuf_g[(size_t)(s * 8 + w) * NQ + gq];
        mall[w] = mbuf_g[(size_t)w * NQ + gq];
    }

    // --- merge 8x10 -> sorted top-16 (insert sequence byte-identical to R17) ---
    unsigned k16[KN];
    #pragma unroll
    for (int s = 0; s < KW; ++s) k16[s] = kall[0][s];
    #pragma unroll
    for (int s = KW; s < KN; ++s) k16[s] = 0x7F800000u | (unsigned)s;  // seeds (> any real)
    #pragma unroll
    for (int w = 1; w < 8; ++w) {
        #pragma unroll
        for (int s = 0; s < KW; ++s) {
            unsigned kk = kall[w][s];
            if (__any(kk < k16[KN - 1])) chain16(k16, kk);  // skip = provable no-op
        }
    }
    float minv = fminf(fminf(fminf(mall[0], mall[1]), fminf(mall[2], mall[3])),
                       fminf(fminf(mall[4], mall[5]), fminf(mall[6], mall[7])));

    // --- violation detect from register-held tenth keys (kall[w][9]) ---
    unsigned flags = 0;
    #pragma unroll
    for (int w = 0; w < 8; ++w)
        flags |= (kall[w][KW - 1] < k16[KN - 1]) ? (1u << w) : 0u;

    if (__any(flags != 0)) {                 // ~0.07 expected events per LAUNCH
        #pragma unroll
        for (int s = 0; s < KN; ++s)
            k16[s] = flags ? (0x7F800000u | (unsigned)s) : k16[s];   // reinit flagged lanes
        #pragma unroll
        for (int w = 0; w < 8; ++w) {
            #pragma unroll
            for (int s = 0; s < KW; ++s) {
                unsigned kk = kall[w][s];
                bool use = (flags != 0) && !((flags >> w) & 1);
                chain16(k16, use ? kk : 0xFFFFFFFFu);          // inf = no-op
            }
        }
        for (int w = 0; w < 8; ++w) {
            if (__any((flags >> w) & 1)) {
                bool actw = ((flags >> w) & 1) != 0;
                for (int t = 0; t < NP / 8; ++t) {
                    int jj = (t << 3) | w;
                    float hx = home[3 * jj], hy = home[3 * jj + 1], hz = home[3 * jj + 2];
                    float hw = dot_rn(hx, hy, hz, hx, hy, hz);
                    float dotj = dot_rn(qx, qy, qz, hx, hy, hz);
                    float d2 = __fsub_rn(__fadd_rn(qq, hw), __fmul_rn(2.f, dotj));
                    unsigned key = (__float_as_uint(d2) & 0xFFFFF800u) | (unsigned)jj;
                    chain16(k16, actw ? key : 0xFFFFFFFFu);
                }
            }
        }
    }

    // --- repulsion: k16 sorted ascending, slot 0 = self (d2=0) -> slots 1..4 ---
    float rep = 0.0f;
    if (predHome) {
        #pragma unroll
        for (int r = 1; r <= 4; ++r) {
            float d2 = __uint_as_float(k16[r] & 0xFFFFF800u);
            float dd = sqrtf(fmaxf(d2, 1e-12f));
            rep += fmaxf(0.02f - dd, 0.0f);
        }
    }

    // --- covariance: load the 16 neighbor points ONCE into regs (independent
    //     loads, one latency); both passes read regs. Values bit-identical to
    //     the old two-pass memory re-read (no intervening writes). ---
    float px[KN], py[KN], pz[KN];
    #pragma unroll
    for (int s = 0; s < KN; ++s) {
        const float* hp = home + 3 * (size_t)(k16[s] & 0x7FFu);
        px[s] = hp[0]; py[s] = hp[1]; pz[s] = hp[2];
    }
    float sx = 0.f, sy = 0.f, sz = 0.f;
    #pragma unroll
    for (int s = 0; s < KN; ++s) { sx += px[s]; sy += py[s]; sz += pz[s]; }
    float mx = sx * (1.0f / KN), my = sy * (1.0f / KN), mz = sz * (1.0f / KN);
    float cxx = 0.f, cxy = 0.f, cxz = 0.f, cyy = 0.f, cyz = 0.f, czz = 0.f;
    #pragma unroll
    for (int s = 0; s < KN; ++s) {
        float ax = px[s] - mx;
        float ay = py[s] - my;
        float az = pz[s] - mz;
        cxx += ax * ax; cxy += ax * ay; cxz += ax * az;
        cyy += ay * ay; cyz += ay * az; czz += az * az;
    }
    cxx *= (1.f / KN); cxy *= (1.f / KN); cxz *= (1.f / KN);
    cyy *= (1.f / KN); cyz *= (1.f / KN); czz *= (1.f / KN);

    // --- normal via faithful ssyevd emulation (register-resident) ---
    float nx, ny, nz;
    ssyevd3_evec0(cxx, cxy, cxz, cyy, cyz, czz, &nx, &ny, &nz);

    // --- wave 1 stages nG; wave 0 dots vs register nP ---
    if (!predHome) {
        sNG[lane * 3 + 0] = nx;
        sNG[lane * 3 + 1] = ny;
        sNG[lane * 3 + 2] = nz;
    }
    __syncthreads();

    double part;
    if (predHome) {
        float gx = sNG[lane * 3 + 0];
        float gy = sNG[lane * 3 + 1];
        float gz = sNG[lane * 3 + 2];
        float dotv = nx * gx + ny * gy + nz * gz;     // fp32, like old dot_kernel terms
        part = (double)minv * (1.0 / (NB * NP))
             + (double)rep  * (0.1 / (NB * NP * 4))
             - (double)dotv * (0.01 / (NB * NP));
    } else {
        part = (double)minv * (1.0 / (NB * NP));
    }

    #pragma unroll
    for (int off = 32; off > 0; off >>= 1) part += __shfl_down(part, off);
    if (lane == 0) wsum[wave] = part;
    __syncthreads();
    if (tid == 0) cdpart[blockIdx.x] = wsum[0] + wsum[1];
}

// ---------------------------------------------------------------------------
// Micro-finalize: 1 wave. Reduce 256 cdpart doubles (4 per lane), write out.
__global__ __launch_bounds__(64) void fin_kernel(
    const double* __restrict__ cdpart, float* __restrict__ out)
{
    int tid = threadIdx.x;
    double c = cdpart[tid] + cdpart[tid + 64] + cdpart[tid + 128] + cdpart[tid + 192];
    #pragma unroll
    for (int off = 32; off > 0; off >>= 1) c += __shfl_down(c, off);
    if (tid == 0)
        out[0] = (float)(c + 0.01);
}

// ---------------------------------------------------------------------------
extern "C" void kernel_launch(void* const* d_in, const int* in_sizes, int n_in,
                              void* d_out, int out_size, void* d_ws, size_t ws_size,
                              hipStream_t stream)
{
    const float* pred = (const float*)d_in[0];
    const float* gt   = (const float*)d_in[1];

    // ws layout: cdpart (256 f64 = 2KB, padded to 4KB) | mbuf_g (1MB) |
    //            kbuf_g (10.5MB). No memset: every slot written before read.
    char* base = (char*)d_ws;
    double*   cdpart = (double*)base;
    float*    mbuf_g = (float*)(base + 4096);
    unsigned* kbuf_g = (unsigned*)(base + 4096 + (size_t)NQ * 8 * 4);

    scan_kernel<<<dim3(NB * 32 * 2), dim3(512), 0, stream>>>(pred, gt, kbuf_g, mbuf_g);
    tail_kernel<<<dim3(256), dim3(128), 0, stream>>>(pred, gt, kbuf_g, mbuf_g, cdpart);
    fin_kernel<<<dim3(1), dim3(64), 0, stream>>>(cdpart, (float*)d_out);
}

// Round 11
// 163.311 us; speedup vs baseline: 1.2799x; 1.0991x over previous
//
#include <hip/hip_runtime.h>

// CombinedLoss: chamfer(pred,gt) + 0.1*repulsion(pred,k=4) + 0.01*(1 - mean(n_pred . n_gt))
// B=8, N=2048, fp32 in, fp32 scalar out.
// Normals match np.linalg.eigh (LAPACK ssyevd) signs point-by-point via faithful
// fp32 ssytd2+ssteqr+sormtr emulation (R3-R7: absmax 0.0).
// R8: branchless sorted-chain top-10 per wave-slice + exact top-16 merge.
// R9: eigensolver state in named registers. R13: masked tail regressed.
// R15-R18 (amputation arc): tail measured latency-bound; wall INVARIANT to
// occupancy (90/73/75us at 2/4/0.5 waves/SIMD) -> tail = one wave's serial
// chain; after load-hoist fix (R18) the residual ~55us is the EIGENSOLVER's
// serial divergent chain (matches R10's standalone eig ~55us).
// R19: a latency chain can only be shortened or OVERLAPPED. R14's fused kernel
// proved the overlap: scan+tail = 112us < 68+65 split (early blocks' eig hides
// under later blocks' scan issue work). R14's sin was its 46us 1-CU fin, not
// fusion. Revive R14's exact fused kernel; dot = 16-block kernel (R10-proven
// fp32 order, ~5us); fin = 1 wave (~2us). 3 launches.

#define NB 8
#define NP 2048
#define KW 10     // per-slice kept keys
#define KN 16

// ---------------- LAPACK helpers (fp32, faithful — DO NOT TOUCH) ----------------

__device__ __forceinline__ float f_slapy2(float x, float y) {
    float xa = fabsf(x), ya = fabsf(y);
    float w = fmaxf(xa, ya), zm = fminf(xa, ya);
    if (zm == 0.f) return w;
    float q = zm / w;
    return w * sqrtf(1.f + q * q);
}

// LAPACK >=3.10 slartg convention: c >= 0 always.
__device__ __forceinline__ void f_slartg(float f, float g, float* cs, float* sn, float* r) {
    if (g == 0.f) { *cs = 1.f; *sn = 0.f; *r = f; }
    else if (f == 0.f) { *cs = 0.f; *sn = copysignf(1.f, g); *r = fabsf(g); }
    else {
        float d = sqrtf(__fadd_rn(__fmul_rn(f, f), __fmul_rn(g, g)));
        *cs = fabsf(f) / d;
        *r  = copysignf(d, f);
        *sn = g / *r;
    }
}

__device__ void f_slaev2(float a, float b, float c,
                         float* rt1, float* rt2, float* cs1, float* sn1) {
    float sm = a + c;
    float df = a - c;
    float adf = fabsf(df);
    float tb = b + b;
    float ab = fabsf(tb);
    float acmx, acmn;
    if (fabsf(a) > fabsf(c)) { acmx = a; acmn = c; } else { acmx = c; acmn = a; }
    float rt;
    if (adf > ab)      { float q = ab / adf; rt = adf * sqrtf(1.f + q * q); }
    else if (adf < ab) { float q = adf / ab; rt = ab * sqrtf(1.f + q * q); }
    else               rt = ab * sqrtf(2.f);
    int sgn1;
    if (sm < 0.f) {
        *rt1 = 0.5f * (sm - rt); sgn1 = -1;
        *rt2 = (acmx / *rt1) * acmn - (b / *rt1) * b;
    } else if (sm > 0.f) {
        *rt1 = 0.5f * (sm + rt); sgn1 = 1;
        *rt2 = (acmx / *rt1) * acmn - (b / *rt1) * b;
    } else {
        *rt1 = 0.5f * rt; *rt2 = -0.5f * rt; sgn1 = 1;
    }
    float cs; int sgn2;
    if (df >= 0.f) { cs = df + rt; sgn2 = 1; }
    else           { cs = df - rt; sgn2 = -1; }
    float acs = fabsf(cs);
    if (acs > ab) {
        float ct = -tb / cs;
        *sn1 = 1.f / sqrtf(1.f + ct * ct);
        *cs1 = ct * *sn1;
    } else {
        if (ab == 0.f) { *cs1 = 1.f; *sn1 = 0.f; }
        else {
            float tn = -cs / tb;
            *cs1 = 1.f / sqrtf(1.f + tn * tn);
            *sn1 = tn * *cs1;
        }
    }
    if (sgn1 == sgn2) { float tn = *cs1; *cs1 = -*sn1; *sn1 = tn; }
}

// --------- register-resident dynamic indexing (R9: replaces scratch arrays) ---------
// Selection only — bit-exact with array loads/stores; compiles to v_cndmask, no memory.

__device__ __forceinline__ float get3(float a, float b, float c, int i) {
    return i == 0 ? a : (i == 1 ? b : c);
}
__device__ __forceinline__ void set3(float& a, float& b, float& c, int i, float v) {
    a = (i == 0) ? v : a;
    b = (i == 1) ? v : b;
    c = (i == 2) ? v : c;
}
__device__ __forceinline__ float get2(float a, float b, int i) { return i == 0 ? a : b; }
__device__ __forceinline__ void set2(float& a, float& b, int i, float v) {
    a = (i == 0) ? v : a;
    b = (i == 1) ? v : b;
}

#define DGET(i)    get3(dd0, dd1, dd2, (i))
#define DSET(i, v) set3(dd0, dd1, dd2, (i), (v))
#define EGET(i)    get2(ee0, ee1, (i))
#define ESET(i, v) set2(ee0, ee1, (i), (v))
#define ZGET(r, c)    get3(z##r##0, z##r##1, z##r##2, (c))
#define ZSET(r, c, v) set3(z##r##0, z##r##1, z##r##2, (c), (v))
// Two-column Givens update: cols (ca,cb) <- (cc*ca - ss*cb, ss*ca + cc*cb), all 3 rows.
#define ZROT(r, ca, cb, cc, ss) { float zt_ = ZGET(r, (ca)); float zb_ = ZGET(r, (cb)); \
    ZSET(r, (ca), (cc) * zt_ - (ss) * zb_); ZSET(r, (cb), (ss) * zt_ + (cc) * zb_); }
#define ZROT3(ca, cb, cc, ss) { ZROT(0, (ca), (cb), (cc), (ss)) ZROT(1, (ca), (cb), (cc), (ss)) ZROT(2, (ca), (cb), (cc), (ss)) }

// fp32 ssyevd for a 3x3 symmetric matrix (lower triangle given), returns
// eigenvector of the SMALLEST eigenvalue, with LAPACK's sign convention.
__device__ void ssyevd3_evec0(float a00, float a10, float a20,
                              float a11, float a21, float a22,
                              float* ox, float* oy, float* oz) {
    // ---- ssytd2('L') ----
    float dd0, dd1, dd2, ee0, ee1;
    float tau = 0.f, v2 = 0.f;
    float xnorm = fabsf(a20);
    if (xnorm == 0.f) {
        tau = 0.f;
        dd0 = a00; dd1 = a11; dd2 = a22; ee0 = a10; ee1 = a21;
    } else {
        float beta = -copysignf(f_slapy2(a10, xnorm), a10);
        tau = (beta - a10) / beta;
        float inv = 1.f / (a10 - beta);
        v2 = a20 * inv;
        float x1 = tau * (a11 + a21 * v2);
        float x2 = tau * (a21 + a22 * v2);
        float alpha = -0.5f * tau * (x1 + x2 * v2);
        float w1 = x1 + alpha;
        float w2 = x2 + alpha * v2;
        float b11 = a11 - 2.f * w1;
        float b21 = a21 - v2 * w1 - w2;
        float b22 = a22 - 2.f * (v2 * w2);
        dd0 = a00; dd1 = b11; dd2 = b22; ee0 = beta; ee1 = b21;
    }
    // ---- ssteqr('I', n=3) ----
    const float eps    = 5.9604645e-08f;
    const float eps2   = eps * eps;
    const float safmin = 1.1754944e-38f;
    const float ssfmax = sqrtf(1.f / safmin) / 3.f;
    const float ssfmin = sqrtf(safmin) / eps2;
    const int n = 3, nmaxit = 90;
    float z00 = 1.f, z01 = 0.f, z02 = 0.f;
    float z10 = 0.f, z11 = 1.f, z12 = 0.f;
    float z20 = 0.f, z21 = 0.f, z22 = 1.f;
    int jtot = 0;
    int l1 = 1;

    while (true) {
        if (l1 > n) break;
        if (l1 > 1) ESET(l1 - 2, 0.f);
        int m = n;
        {   // for (mi = l1; mi <= n-1; ++mi) with first-hit break
            bool found = false;
            #pragma unroll
            for (int mi = 1; mi <= 2; ++mi) {
                if (!found && mi >= l1) {
                    float tst = fabsf(EGET(mi - 1));
                    if (tst == 0.f) { m = mi; found = true; }
                    else if (tst <= (sqrtf(fabsf(DGET(mi - 1))) * sqrtf(fabsf(DGET(mi)))) * eps) {
                        ESET(mi - 1, 0.f); m = mi; found = true;
                    }
                }
            }
        }
        int l = l1, lsv = l, lend = m, lendsv = lend;
        l1 = m + 1;
        if (lend == l) continue;

        float anorm = 0.f;
        #pragma unroll
        for (int i = 1; i <= 3; ++i)
            if (i >= l && i <= lend) anorm = fmaxf(anorm, fabsf(DGET(i - 1)));
        #pragma unroll
        for (int i = 1; i <= 2; ++i)
            if (i >= l && i <= lend - 1) anorm = fmaxf(anorm, fabsf(EGET(i - 1)));
        int iscale = 0; float sclto = 1.f;
        if (anorm == 0.f) continue;
        if (anorm > ssfmax) { iscale = 1; sclto = ssfmax; }
        else if (anorm < ssfmin) { iscale = 2; sclto = ssfmin; }
        if (iscale) {
            float mul = sclto / anorm;
            #pragma unroll
            for (int i = 1; i <= 3; ++i)
                if (i >= l && i <= lend) DSET(i - 1, DGET(i - 1) * mul);
            #pragma unroll
            for (int i = 1; i <= 2; ++i)
                if (i >= l && i <= lend - 1) ESET(i - 1, EGET(i - 1) * mul);
        }
        if (fabsf(DGET(lend - 1)) < fabsf(DGET(l - 1))) { lend = lsv; l = lendsv; }

        if (lend > l) {
            // QL
            while (true) {
                int mq = lend;
                if (l != lend) {
                    bool found = false;
                    #pragma unroll
                    for (int i = 1; i <= 2; ++i) {
                        if (!found && i >= l && i <= lend - 1) {
                            float ei = EGET(i - 1);
                            float tst = ei * ei;
                            if (tst <= (eps2 * fabsf(DGET(i - 1))) * fabsf(DGET(i)) + safmin) { mq = i; found = true; }
                        }
                    }
                }
                if (mq < lend) ESET(mq - 1, 0.f);
                float p = DGET(l - 1);
                if (mq == l) { DSET(l - 1, p); l = l + 1; if (l <= lend) continue; break; }
                if (mq == l + 1) {
                    float rt1, rt2, c, s;
                    f_slaev2(DGET(l - 1), EGET(l - 1), DGET(l), &rt1, &rt2, &c, &s);
                    ZROT3(l, l - 1, c, s);
                    DSET(l - 1, rt1); DSET(l, rt2); ESET(l - 1, 0.f);
                    l += 2; if (l <= lend) continue; break;
                }
                if (jtot == nmaxit) break;
                jtot++;
                float g = (DGET(l) - p) / (2.f * EGET(l - 1));
                float r = f_slapy2(g, 1.f);
                g = DGET(mq - 1) - p + EGET(l - 1) / (g + copysignf(r, g));
                float s = 1.f, c = 1.f; p = 0.f;
                float cw0 = 0.f, cw1 = 0.f, sw0 = 0.f, sw1 = 0.f;
                // for (i = mq-1; i >= l; --i)
                #pragma unroll
                for (int i = 2; i >= 1; --i) {
                    if (i <= mq - 1 && i >= l) {
                        float f = s * EGET(i - 1);
                        float b = c * EGET(i - 1);
                        f_slartg(g, f, &c, &s, &r);
                        if (i != mq - 1) ESET(i, r);
                        g = DGET(i) - p;
                        r = (DGET(i - 1) - g) * s + 2.f * c * b;
                        p = s * r;
                        DSET(i, g + p);
                        g = c * r - b;
                        set2(cw0, cw1, i - l, c);
                        set2(sw0, sw1, i - l, -s);
                    }
                }
                // for (j = mq-l; j >= 1; --j)
                #pragma unroll
                for (int j = 2; j >= 1; --j) {
                    if (j <= mq - l) {
                        float cj = get2(cw0, cw1, j - 1), sj = get2(sw0, sw1, j - 1);
                        int c0 = l - 1 + (j - 1);
                        ZROT3(c0 + 1, c0, cj, sj);
                    }
                }
                DSET(l - 1, DGET(l - 1) - p);
                ESET(l - 1, g);
            }
        } else {
            // QR
            while (true) {
                int mq = lend;
                if (l != lend) {
                    bool found = false;
                    // for (i = l; i >= lend+1; --i)
                    #pragma unroll
                    for (int i = 3; i >= 2; --i) {
                        if (!found && i <= l && i >= lend + 1) {
                            float ei = EGET(i - 2);
                            float tst = ei * ei;
                            if (tst <= (eps2 * fabsf(DGET(i - 1))) * fabsf(DGET(i - 2)) + safmin) { mq = i; found = true; }
                        }
                    }
                }
                if (mq > lend) ESET(mq - 2, 0.f);
                float p = DGET(l - 1);
                if (mq == l) { DSET(l - 1, p); l = l - 1; if (l >= lend) continue; break; }
                if (mq == l - 1) {
                    float rt1, rt2, c, s;
                    f_slaev2(DGET(l - 2), EGET(l - 2), DGET(l - 1), &rt1, &rt2, &c, &s);
                    ZROT3(l - 1, l - 2, c, s);
                    DSET(l - 2, rt1); DSET(l - 1, rt2); ESET(l - 2, 0.f);
                    l -= 2; if (l >= lend) continue; break;
                }
                if (jtot == nmaxit) break;
                jtot++;
                float g = (DGET(l - 2) - p) / (2.f * EGET(l - 2));
                float r = f_slapy2(g, 1.f);
                g = DGET(mq - 1) - p + EGET(l - 2) / (g + copysignf(r, g));
                float s = 1.f, c = 1.f; p = 0.f;
                float cw0 = 0.f, cw1 = 0.f, sw0 = 0.f, sw1 = 0.f;
                // for (i = mq; i <= l-1; ++i)
                #pragma unroll
                for (int i = 1; i <= 2; ++i) {
                    if (i >= mq && i <= l - 1) {
                        float f = s * EGET(i - 1);
                        float b = c * EGET(i - 1);
                        f_slartg(g, f, &c, &s, &r);
                        if (i != mq) ESET(i - 2, r);
                        g = DGET(i - 1) - p;
                        r = (DGET(i) - g) * s + 2.f * c * b;
                        p = s * r;
                        DSET(i - 1, g + p);
                        g = c * r - b;
                        set2(cw0, cw1, i - mq, c);
                        set2(sw0, sw1, i - mq, s);
                    }
                }
                // for (j = 1; j <= l-mq; ++j)
                #pragma unroll
                for (int j = 1; j <= 2; ++j) {
                    if (j <= l - mq) {
                        float cj = get2(cw0, cw1, j - 1), sj = get2(sw0, sw1, j - 1);
                        int c0 = mq - 1 + (j - 1);
                        ZROT3(c0 + 1, c0, cj, sj);
                    }
                }
                DSET(l - 1, DGET(l - 1) - p);
                ESET(l - 2, g);
            }
        }
        if (iscale) {
            float mul = anorm / sclto;
            #pragma unroll
            for (int i = 1; i <= 3; ++i)
                if (i >= lsv && i <= lendsv) DSET(i - 1, DGET(i - 1) * mul);
            #pragma unroll
            for (int i = 1; i <= 2; ++i)
                if (i >= lsv && i <= lendsv - 1) ESET(i - 1, EGET(i - 1) * mul);
        }
        if (jtot >= nmaxit) break;
    }

    // sort ascending (column swaps — no sign change)
    #pragma unroll
    for (int ii = 2; ii <= 3; ++ii) {
        int i = ii - 1, k = i;
        float p = DGET(i - 1);
        #pragma unroll
        for (int j = ii; j <= 3; ++j)
            if (DGET(j - 1) < p) { k = j; p = DGET(j - 1); }
        if (k != i) {
            DSET(k - 1, DGET(i - 1)); DSET(i - 1, p);
            { float t0 = ZGET(0, i - 1); ZSET(0, i - 1, ZGET(0, k - 1)); ZSET(0, k - 1, t0); }
            { float t1 = ZGET(1, i - 1); ZSET(1, i - 1, ZGET(1, k - 1)); ZSET(1, k - 1, t1); }
            { float t2 = ZGET(2, i - 1); ZSET(2, i - 1, ZGET(2, k - 1)); ZSET(2, k - 1, t2); }
        }
    }
    // sormtr('L','L','N')
    float r0 = z00, r1 = z10, r2 = z20;
    if (tau != 0.f) {
        float sum = r1 + v2 * r2;
        r1 -= tau * sum;
        r2 -= tau * (v2 * sum);
    }
    *ox = r0; *oy = r1; *oz = r2;
}

// ---------------- common ----------------

__device__ __forceinline__ float dot_rn(float ax, float ay, float az,
                                        float bx, float by, float bz) {
    return __fadd_rn(__fadd_rn(__fmul_rn(ax, bx), __fmul_rn(ay, by)), __fmul_rn(az, bz));
}

// Branchless sorted-chain inserts: keys ascending; drops the largest.
__device__ __forceinline__ void chain10(unsigned k[KW], unsigned x) {
    unsigned t = x;
    #pragma unroll
    for (int s = 0; s < KW; ++s) {
        unsigned lo = k[s] < t ? k[s] : t;
        unsigned hi = k[s] < t ? t : k[s];
        k[s] = lo; t = hi;
    }
}
__device__ __forceinline__ void chain16(unsigned k[KN], unsigned x) {
    unsigned t = x;
    #pragma unroll
    for (int s = 0; s < KN; ++s) {
        unsigned lo = k[s] < t ? k[s] : t;
        unsigned hi = k[s] < t ? t : k[s];
        k[s] = lo; t = hi;
    }
}

// ---------------- fused scan + wave-0 full-pack tail (R14, proven) ----------------
// 512 blocks x 512 threads (8 waves), 2 blocks/CU (64KB LDS).
// Phase 1 (scan): wave w scans interleaved slice j=8t+w, branchless sorted top-10
//   per lane-query + chamfer partial min. Publish to LDS.
// Phase 2 (tail): wave 0 ONLY, fully packed: 64 lanes = 64 queries. The eig
//   chain of early blocks overlaps with later blocks' scan issue-work (2
//   blocks/CU) — measured 112us fused vs 68+65 split.
#define KIDX(s, w, l) (((s) * 8 + (w)) * 64 + (l))

__global__ __launch_bounds__(512, 4) void scan_kernel(
    const float* __restrict__ pred, const float* __restrict__ gt,
    float* __restrict__ nP, float* __restrict__ nG,
    double* __restrict__ cdpart)
{
    __shared__ float4 sHome[NP];            // (x,y,z,|p|^2)  32 KB — stays live (fallback + gather)
    __shared__ float4 sOther[NP];           // (x,y,z,0)      32 KB — aliased post-scan
    unsigned* kbuf = (unsigned*)sOther;                       // [10][8][64] u32 = 20 KB
    float* mbuf = (float*)((char*)sOther + 20480);            // [8][64] f32 = 2 KB

    int bi = blockIdx.x;
    bool predHome = bi < NB * 32;
    int lb = predHome ? bi : bi - NB * 32;
    int b = lb >> 5;
    int tile = lb & 31;
    int tid  = threadIdx.x;
    int wave = tid >> 6;
    int lane = tid & 63;

    const float* home  = (predHome ? pred : gt) + (size_t)b * NP * 3;
    const float* other = (predHome ? gt : pred) + (size_t)b * NP * 3;

    for (int t = tid; t < NP; t += 512) {
        float hx = home[3 * t], hy = home[3 * t + 1], hz = home[3 * t + 2];
        sHome[t] = make_float4(hx, hy, hz, dot_rn(hx, hy, hz, hx, hy, hz));
        float ox = other[3 * t], oy = other[3 * t + 1], oz = other[3 * t + 2];
        sOther[t] = make_float4(ox, oy, oz, 0.f);
    }
    __syncthreads();

    int im = tile * 64 + lane;              // original index of this lane's query
    float4 qv = sHome[im];
    float qx = qv.x, qy = qv.y, qz = qv.z, qq = qv.w;

    unsigned keys[KW];
    #pragma unroll
    for (int s = 0; s < KW; ++s) keys[s] = 0x7F800000u | (unsigned)s;  // sorted inf seeds

    float minv = 1e30f;

    for (int t = 0; t < NP / 8; ++t) {
        int jj = (t << 3) | wave;
        float4 h = sHome[jj];                                  // broadcast b128
        float dotj = dot_rn(qx, qy, qz, h.x, h.y, h.z);
        float d2 = __fsub_rn(__fadd_rn(qq, h.w), __fmul_rn(2.f, dotj));
        chain10(keys, (__float_as_uint(d2) & 0xFFFFF800u) | (unsigned)jj);
        float4 o = sOther[jj];                                 // broadcast b128
        float ex = qx - o.x, ey = qy - o.y, ez = qz - o.z;
        minv = fminf(minv, fmaf(ex, ex, fmaf(ey, ey, ez * ez)));
    }
    __syncthreads();   // all sOther reads done before kbuf aliasing writes

    // publish per-wave sorted top-10 + chamfer partial min
    #pragma unroll
    for (int s = 0; s < KW; ++s) kbuf[KIDX(s, wave, lane)] = keys[s];
    mbuf[wave * 64 + lane] = minv;
    __syncthreads();

    if (wave != 0) return;

    // ---------------- tail: wave 0, fully packed (64 lanes = 64 queries) ----------------
    // --- merge 8x10 -> sorted top-16 (insert sequence identical to R9/R10) ---
    unsigned k16[KN];
    #pragma unroll
    for (int s = 0; s < KW; ++s) k16[s] = keys[s];             // own sorted 10
    #pragma unroll
    for (int s = KW; s < KN; ++s) k16[s] = 0x7F800000u | (unsigned)s;  // seeds (> any real)
    for (int w = 1; w < 8; ++w) {
        #pragma unroll
        for (int s = 0; s < KW; ++s) chain16(k16, kbuf[KIDX(s, w, lane)]);
    }
    minv = fminf(fminf(fminf(mbuf[lane], mbuf[64 + lane]),
                       fminf(mbuf[128 + lane], mbuf[192 + lane])),
                 fminf(fminf(mbuf[256 + lane], mbuf[320 + lane]),
                       fminf(mbuf[384 + lane], mbuf[448 + lane])));

    // --- violation detect: slice may hide a top-16 member iff its 10th-best
    //     (kbuf slot 9, sorted) < pool 16th (k16[15]). Exact repair below. ---
    unsigned flags = 0;
    #pragma unroll
    for (int w = 0; w < 8; ++w)
        flags |= (kbuf[KIDX(KW - 1, w, lane)] < k16[15]) ? (1u << w) : 0u;

    if (__any(flags != 0)) {                 // ~0.07 expected events per LAUNCH
        #pragma unroll
        for (int s = 0; s < KN; ++s)
            k16[s] = flags ? (0x7F800000u | (unsigned)s) : k16[s];   // reinit flagged lanes
        for (int w = 0; w < 8; ++w) {
            #pragma unroll
            for (int s = 0; s < KW; ++s) {
                unsigned kk = kbuf[KIDX(s, w, lane)];
                bool use = (flags != 0) && !((flags >> w) & 1);
                chain16(k16, use ? kk : 0xFFFFFFFFu);          // inf = no-op
            }
        }
        for (int w = 0; w < 8; ++w) {
            if (__any((flags >> w) & 1)) {
                bool actw = ((flags >> w) & 1) != 0;
                for (int t = 0; t < NP / 8; ++t) {
                    int jj = (t << 3) | w;
                    float4 h = sHome[jj];
                    float dotj = dot_rn(qx, qy, qz, h.x, h.y, h.z);
                    float d2 = __fsub_rn(__fadd_rn(qq, h.w), __fmul_rn(2.f, dotj));
                    unsigned key = (__float_as_uint(d2) & 0xFFFFF800u) | (unsigned)jj;
                    chain16(k16, actw ? key : 0xFFFFFFFFu);
                }
            }
        }
    }

    // --- repulsion: k16 sorted ascending, slot 0 = self (d2=0) -> slots 1..4 ---
    float rep = 0.0f;
    if (predHome) {
        #pragma unroll
        for (int r = 1; r <= 4; ++r) {
            float d2 = __uint_as_float(k16[r] & 0xFFFFF800u);
            float dd = sqrtf(fmaxf(d2, 1e-12f));
            rep += fmaxf(0.02f - dd, 0.0f);
        }
    }

    // --- covariance over the 16-NN: gather from sHome (bit-identical values) ---
    float sx = 0.f, sy = 0.f, sz = 0.f;
    #pragma unroll
    for (int s = 0; s < KN; ++s) {
        float4 p = sHome[k16[s] & 0x7FFu];
        sx += p.x; sy += p.y; sz += p.z;
    }
    float mx = sx * (1.0f / KN), my = sy * (1.0f / KN), mz = sz * (1.0f / KN);
    float cxx = 0.f, cxy = 0.f, cxz = 0.f, cyy = 0.f, cyz = 0.f, czz = 0.f;
    #pragma unroll
    for (int s = 0; s < KN; ++s) {
        float4 p = sHome[k16[s] & 0x7FFu];
        float ax = p.x - mx;
        float ay = p.y - my;
        float az = p.z - mz;
        cxx += ax * ax; cxy += ax * ay; cxz += ax * az;
        cyy += ay * ay; cyz += ay * az; czz += az * az;
    }
    cxx *= (1.f / KN); cxy *= (1.f / KN); cxz *= (1.f / KN);
    cyy *= (1.f / KN); cyz *= (1.f / KN); czz *= (1.f / KN);

    // --- normal via faithful ssyevd emulation (register-resident) ---
    float nx, ny, nz;
    ssyevd3_evec0(cxx, cxy, cxz, cyy, cyz, czz, &nx, &ny, &nz);

    float* nout = predHome ? nP : nG;
    int gi = b * NP + im;
    nout[gi * 3 + 0] = nx;
    nout[gi * 3 + 1] = ny;
    nout[gi * 3 + 2] = nz;

    double part = (double)minv * (1.0 / (NB * NP))
                + (double)rep  * (0.1 / (NB * NP * 4));

    #pragma unroll
    for (int off = 32; off > 0; off >>= 1) part += __shfl_down(part, off);
    if (lane == 0) cdpart[bi] = part;
}

// ---------------------------------------------------------------------------
// Normal-dot partials: 16 blocks x 64 threads = the R10-proven per-thread fp32
// summation order (vt = bid*64+tid, stride 1024); plain-stores dotpart[bid].
__global__ __launch_bounds__(64) void dot_kernel(
    const float* __restrict__ nP, const float* __restrict__ nG,
    double* __restrict__ dotpart)
{
    int vt = blockIdx.x * 64 + threadIdx.x;   // 0..1023
    float s = 0.f;
    for (int i = vt; i < NB * NP; i += 1024)
        s += nP[3 * i] * nG[3 * i] + nP[3 * i + 1] * nG[3 * i + 1] + nP[3 * i + 2] * nG[3 * i + 2];
    double part = (double)s;
    #pragma unroll
    for (int off = 32; off > 0; off >>= 1) part += __shfl_down(part, off);
    if (threadIdx.x == 0) dotpart[blockIdx.x] = part;
}

// ---------------------------------------------------------------------------
// Micro-finalize: 1 wave. Reduce 512 cdpart (8/lane) + 16 dotpart doubles.
__global__ __launch_bounds__(64) void fin_kernel(
    const double* __restrict__ cdpart, const double* __restrict__ dotpart,
    float* __restrict__ out)
{
    int tid = threadIdx.x;
    double c = 0.0;
    #pragma unroll
    for (int k = 0; k < 8; ++k) c += cdpart[tid + 64 * k];
    double d = (tid < 16) ? dotpart[tid] : 0.0;
    #pragma unroll
    for (int off = 32; off > 0; off >>= 1) {
        c += __shfl_down(c, off);
        d += __shfl_down(d, off);
    }
    if (tid == 0)
        out[0] = (float)(c - d * (0.01 / (NB * NP)) + 0.01);
}

// ---------------------------------------------------------------------------
extern "C" void kernel_launch(void* const* d_in, const int* in_sizes, int n_in,
                              void* d_out, int out_size, void* d_ws, size_t ws_size,
                              hipStream_t stream)
{
    const float* pred = (const float*)d_in[0];
    const float* gt   = (const float*)d_in[1];

    // ws layout: nP (192KB) | nG (192KB) | cdpart (512 f64 = 4KB) | dotpart (16 f64).
    // No memset: every slot written before read (stream order).
    char* base = (char*)d_ws;
    float*  nP      = (float*)base;
    float*  nG      = nP + (size_t)NB * NP * 3;
    double* cdpart  = (double*)(nG + (size_t)NB * NP * 3);
    double* dotpart = cdpart + 512;

    scan_kernel<<<dim3(NB * 32 * 2), dim3(512), 0, stream>>>(pred, gt, nP, nG, cdpart);
    dot_kernel<<<dim3(16), dim3(64), 0, stream>>>(nP, nG, dotpart);
    fin_kernel<<<dim3(1), dim3(64), 0, stream>>>(cdpart, dotpart, (float*)d_out);
}